// Round 11
// baseline (276.728 us; speedup 1.0000x reference)
//
#include <hip/hip_runtime.h>
#include <hip/hip_fp16.h>

#define N_NODES 100000
#define N_EDGES 1600000
#define NCLS 40
#define NBUCK 196          // buckets of 512 nodes; bucket = id >> 9
#define CAPE 8960          // per-bucket edge capacity
#define CAPC 10752         // per-bucket CSR capacity incl. x8 padding
#define DUMMY N_NODES      // pad source id; row DUMMY zeroed, packed w = 0

typedef unsigned short u16;
typedef unsigned int u32;
typedef short bf16x8 __attribute__((ext_vector_type(8)));
typedef float f32x4 __attribute__((ext_vector_type(4)));

static inline size_t align256(size_t x) { return (x + 255) & ~(size_t)255; }

__device__ __forceinline__ float bf2f(u16 h) { return __uint_as_float(((u32)h) << 16); }
__device__ __forceinline__ u16 f2bf(float f) {
    u32 u = __float_as_uint(f);
    u += 0x7FFFu + ((u >> 16) & 1u);  // round-to-nearest-even
    return (u16)(u >> 16);
}
__device__ __forceinline__ u32 pk2(u16 a, u16 b) { return (u32)a | ((u32)b << 16); }
__device__ __forceinline__ u32 pack15(float f) {   // positive fp16 sans sign bit
    return ((u32)__half_as_ushort(__float2half(f))) & 0x7FFFu;
}
__device__ __forceinline__ float unpack15(u32 bits) {
    return __half2float(__ushort_as_half((u16)bits));
}

// ---------- pass 1: LDS-histogram partition by bucket + fused x->bf16 ----------
#define PS_BLOCKS 391
#define CONV_BLOCKS 6250

__global__ __launch_bounds__(256) void pscatter_conv(const int* __restrict__ src,
                                                     const int* __restrict__ dst,
                                                     int* __restrict__ gFillD,
                                                     int* __restrict__ gFillS,
                                                     u32* __restrict__ partD,
                                                     int* __restrict__ partS,
                                                     const float* __restrict__ x,
                                                     u16* __restrict__ xb) {
    if (blockIdx.x >= PS_BLOCKS) {
        int i = (blockIdx.x - PS_BLOCKS) * 256 + threadIdx.x;  // 4 floats/thread
        float4 v = *(const float4*)(x + (size_t)i * 4);
        ushort4 o;
        o.x = f2bf(v.x); o.y = f2bf(v.y); o.z = f2bf(v.z); o.w = f2bf(v.w);
        *(ushort4*)(xb + (size_t)i * 4) = o;
        return;
    }
    __shared__ int histD[NBUCK], histS[NBUCK], chunkD[NBUCK], chunkS[NBUCK];
    int tid = threadIdx.x;
    int base = blockIdx.x * 4096;

    int4 sv[4], dv[4];
#pragma unroll
    for (int j = 0; j < 4; ++j) {
        int idx = base + j * 1024 + tid * 4;
        if (idx < N_EDGES) {
            sv[j] = *(const int4*)(src + idx);
            dv[j] = *(const int4*)(dst + idx);
        } else {
            sv[j] = make_int4(0, 0, 0, 0);
            dv[j] = make_int4(0, 0, 0, 0);
        }
    }

    for (int i = tid; i < NBUCK; i += 256) { histD[i] = 0; histS[i] = 0; }
    __syncthreads();
#pragma unroll
    for (int j = 0; j < 4; ++j)
#pragma unroll
        for (int k = 0; k < 4; ++k) {
            int s = ((const int*)&sv[j])[k], d = ((const int*)&dv[j])[k];
            if (s != d) {
                atomicAdd(&histD[d >> 9], 1);
                atomicAdd(&histS[s >> 9], 1);
            }
        }
    __syncthreads();
    for (int B = tid; B < NBUCK; B += 256) {
        int cD = histD[B];
        chunkD[B] = cD ? atomicAdd(&gFillD[B], cD) : 0;
        int cS = histS[B];
        chunkS[B] = cS ? atomicAdd(&gFillS[B], cS) : 0;
    }
    __syncthreads();
    for (int i = tid; i < NBUCK; i += 256) { histD[i] = 0; histS[i] = 0; }
    __syncthreads();
#pragma unroll
    for (int j = 0; j < 4; ++j)
#pragma unroll
        for (int k = 0; k < 4; ++k) {
            int s = ((const int*)&sv[j])[k], d = ((const int*)&dv[j])[k];
            if (s != d) {
                int bD = d >> 9;
                int r = atomicAdd(&histD[bD], 1);
                int o = chunkD[bD] + r;
                if (o < CAPE) partD[bD * CAPE + o] = ((u32)s << 9) | (u32)(d & 511);
                int bS = s >> 9;
                int r2 = atomicAdd(&histS[bS], 1);
                int o2 = chunkS[bS] + r2;
                if (o2 < CAPE) partS[bS * CAPE + o2] = s;
            }
        }
}

// ---------- pass 2a: src-side out-degree histogram -> dis (must finish before csr pack) ----------
__global__ __launch_bounds__(256) void build_dis(const int* __restrict__ partS,
                                                 const int* __restrict__ gFillS,
                                                 float* __restrict__ dis) {
    __shared__ int cnt[512];
    int tid = threadIdx.x;
    int B = blockIdx.x;
    for (int i = tid; i < 512; i += 256) cnt[i] = 0;
    __syncthreads();
    int nS = min(gFillS[B], CAPE);
    for (int i = tid; i < nS; i += 256) atomicAdd(&cnt[partS[B * CAPE + i] & 511], 1);
    __syncthreads();
    for (int n = tid; n < 512; n += 256) {
        int node = B * 512 + n;
        if (node < N_NODES) {
            int dg = cnt[n];
            dis[node] = dg > 0 ? 1.0f / sqrtf((float)dg) : 0.0f;
        }
    }
}

// ---------- pass 2b: per-bucket CSR build; entry = src | fp15(dis[src])<<17 ----------
__global__ __launch_bounds__(256) void build_csr(const u32* __restrict__ partD,
                                                 const int* __restrict__ gFillD,
                                                 const float* __restrict__ dis,
                                                 u32* __restrict__ csr,
                                                 int2* __restrict__ meta) {
    __shared__ int cnt[512], loc[512], rnk[512];
    int tid = threadIdx.x;
    int B = blockIdx.x;
    for (int i = tid; i < 512; i += 256) { cnt[i] = 0; rnk[i] = 0; }
    __syncthreads();
    int nD = min(gFillD[B], CAPE);
    for (int i = tid; i < nD; i += 256) atomicAdd(&cnt[partD[B * CAPE + i] & 511], 1);
    __syncthreads();
    if (tid < 64) {
        int bb = tid * 8, c8[8], mysum = 0;
#pragma unroll
        for (int j = 0; j < 8; ++j) { c8[j] = (cnt[bb + j] + 7) & ~7; mysum += c8[j]; }
        int incl = mysum;
#pragma unroll
        for (int off = 1; off < 64; off <<= 1) {
            int v = __shfl_up(incl, off);
            if (tid >= off) incl += v;
        }
        int run = incl - mysum;
#pragma unroll
        for (int j = 0; j < 8; ++j) { loc[bb + j] = run; run += c8[j]; }
    }
    __syncthreads();
    for (int n = tid; n < 512; n += 256) {
        int node = B * 512 + n;
        if (node < N_NODES) {
            meta[node] = make_int2(B * CAPC + loc[n], cnt[n]);
            int c = cnt[n], c8 = (c + 7) & ~7;   // pad list to x8 with DUMMY (w bits = 0)
            for (int e = c; e < c8; ++e) csr[B * CAPC + loc[n] + e] = (u32)DUMMY;
        }
    }
    for (int i = tid; i < nD; i += 256) {
        u32 p = partD[B * CAPE + i];
        int ln = p & 511;
        u32 s = p >> 9;
        int r = atomicAdd(&rnk[ln], 1);
        int pos = loc[ln] + r;
        if (pos < CAPC) csr[B * CAPC + pos] = s | (pack15(dis[s]) << 17);
    }
}

// ---------- SPMM pair-gather, packed weights (no per-edge dis load) ----------
// lanes 0-31: even edges, lanes 32-63: odd edges; each lane covers 2 features (u32).
// entry e: src = e & 0x1FFFF, w = fp15(e >> 17). v = -dis[node] * sum w_s * in[s,:].
__global__ __launch_bounds__(256) void spmm(const u16* __restrict__ in,     // (N+1)x64 bf16
                                            const float* __restrict__ dis,
                                            const int2* __restrict__ meta,
                                            const u32* __restrict__ csr,
                                            u16* __restrict__ outhi,
                                            u16* __restrict__ outlo) {
    int node = (blockIdx.x * 256 + threadIdx.x) >> 6;
    int lane = threadIdx.x & 63;
    if (node >= N_NODES) return;
    int2 mt = meta[node];
    int c8 = (mt.y + 7) & ~7;          // lists DUMMY-padded to x8
    const u32* lst = csr + mt.x;       // 32B-aligned
    const u32* in32 = (const u32*)in;
    const int hsel = lane >> 5;
    const int fl = lane & 31;
    float acc0 = 0.0f, acc1 = 0.0f;
    int e = 0;
    for (; e + 16 <= c8; e += 16) {     // 8 independent row-pair loads in flight
        uint4 ea = *(const uint4*)(lst + e);
        uint4 eb = *(const uint4*)(lst + e + 4);
        uint4 ec = *(const uint4*)(lst + e + 8);
        uint4 ed = *(const uint4*)(lst + e + 12);
        u32 e0 = hsel ? ea.y : ea.x;
        u32 e1 = hsel ? ea.w : ea.z;
        u32 e2 = hsel ? eb.y : eb.x;
        u32 e3 = hsel ? eb.w : eb.z;
        u32 e4 = hsel ? ec.y : ec.x;
        u32 e5 = hsel ? ec.w : ec.z;
        u32 e6 = hsel ? ed.y : ed.x;
        u32 e7 = hsel ? ed.w : ed.z;
        u32 v0 = in32[((e0 & 0x1FFFFu) << 5) + fl];
        u32 v1 = in32[((e1 & 0x1FFFFu) << 5) + fl];
        u32 v2 = in32[((e2 & 0x1FFFFu) << 5) + fl];
        u32 v3 = in32[((e3 & 0x1FFFFu) << 5) + fl];
        u32 v4 = in32[((e4 & 0x1FFFFu) << 5) + fl];
        u32 v5 = in32[((e5 & 0x1FFFFu) << 5) + fl];
        u32 v6 = in32[((e6 & 0x1FFFFu) << 5) + fl];
        u32 v7 = in32[((e7 & 0x1FFFFu) << 5) + fl];
        float w0 = unpack15(e0 >> 17), w1 = unpack15(e1 >> 17);
        float w2 = unpack15(e2 >> 17), w3 = unpack15(e3 >> 17);
        float w4 = unpack15(e4 >> 17), w5 = unpack15(e5 >> 17);
        float w6 = unpack15(e6 >> 17), w7 = unpack15(e7 >> 17);
        acc0 = fmaf(w0, __uint_as_float(v0 << 16), acc0);
        acc1 = fmaf(w0, __uint_as_float(v0 & 0xFFFF0000u), acc1);
        acc0 = fmaf(w1, __uint_as_float(v1 << 16), acc0);
        acc1 = fmaf(w1, __uint_as_float(v1 & 0xFFFF0000u), acc1);
        acc0 = fmaf(w2, __uint_as_float(v2 << 16), acc0);
        acc1 = fmaf(w2, __uint_as_float(v2 & 0xFFFF0000u), acc1);
        acc0 = fmaf(w3, __uint_as_float(v3 << 16), acc0);
        acc1 = fmaf(w3, __uint_as_float(v3 & 0xFFFF0000u), acc1);
        acc0 = fmaf(w4, __uint_as_float(v4 << 16), acc0);
        acc1 = fmaf(w4, __uint_as_float(v4 & 0xFFFF0000u), acc1);
        acc0 = fmaf(w5, __uint_as_float(v5 << 16), acc0);
        acc1 = fmaf(w5, __uint_as_float(v5 & 0xFFFF0000u), acc1);
        acc0 = fmaf(w6, __uint_as_float(v6 << 16), acc0);
        acc1 = fmaf(w6, __uint_as_float(v6 & 0xFFFF0000u), acc1);
        acc0 = fmaf(w7, __uint_as_float(v7 << 16), acc0);
        acc1 = fmaf(w7, __uint_as_float(v7 & 0xFFFF0000u), acc1);
    }
    if (e < c8) {                      // remainder: exactly 8 edges
        uint4 ea = *(const uint4*)(lst + e);
        uint4 eb = *(const uint4*)(lst + e + 4);
        u32 e0 = hsel ? ea.y : ea.x;
        u32 e1 = hsel ? ea.w : ea.z;
        u32 e2 = hsel ? eb.y : eb.x;
        u32 e3 = hsel ? eb.w : eb.z;
        u32 v0 = in32[((e0 & 0x1FFFFu) << 5) + fl];
        u32 v1 = in32[((e1 & 0x1FFFFu) << 5) + fl];
        u32 v2 = in32[((e2 & 0x1FFFFu) << 5) + fl];
        u32 v3 = in32[((e3 & 0x1FFFFu) << 5) + fl];
        float w0 = unpack15(e0 >> 17), w1 = unpack15(e1 >> 17);
        float w2 = unpack15(e2 >> 17), w3 = unpack15(e3 >> 17);
        acc0 = fmaf(w0, __uint_as_float(v0 << 16), acc0);
        acc1 = fmaf(w0, __uint_as_float(v0 & 0xFFFF0000u), acc1);
        acc0 = fmaf(w1, __uint_as_float(v1 << 16), acc0);
        acc1 = fmaf(w1, __uint_as_float(v1 & 0xFFFF0000u), acc1);
        acc0 = fmaf(w2, __uint_as_float(v2 << 16), acc0);
        acc1 = fmaf(w2, __uint_as_float(v2 & 0xFFFF0000u), acc1);
        acc0 = fmaf(w3, __uint_as_float(v3 << 16), acc0);
        acc1 = fmaf(w3, __uint_as_float(v3 & 0xFFFF0000u), acc1);
    }
    acc0 += __shfl_xor(acc0, 32);
    acc1 += __shfl_xor(acc1, 32);
    float vd = -dis[node];
    float f0 = vd * acc0, f1 = vd * acc1;
    u32 o32 = ((u32)node << 5) + fl;
    u16 h0 = f2bf(f0), h1 = f2bf(f1);
    if (hsel == 0) {
        ((u32*)outhi)[o32] = pk2(h0, h1);
    } else {
        ((u32*)outlo)[o32] = pk2(f2bf(f0 - bf2f(h0)), f2bf(f1 - bf2f(h1)));
    }
}

// ---------- dense via MFMA, split-bf16, Chebyshev fold in the weights ----------
// out = A0@(W0 - W2) + A1@W1 + Ty@(2*W2)   where Ty = L.A1
#define DGRID 625
#define DNT 10             // 625 * 10 * 16 = 100000 rows exactly
#define LSTR 200           // u16 per LDS row (192 data + 8 pad)

__device__ __forceinline__ float foldW(const float* __restrict__ W, int kk, int col,
                                       int ncols) {
    float wv = W[kk * ncols + col];
    if (kk < 64) wv -= W[(kk + 128) * ncols + col];   // W0 - W2
    else if (kk >= 128) wv += wv;                     // 2 * W2
    return wv;
}

__global__ __launch_bounds__(256) void dense1_mf(const float* __restrict__ x,
                                                 const u16* __restrict__ a1h,
                                                 const u16* __restrict__ a1l,
                                                 const u16* __restrict__ tyh,
                                                 const u16* __restrict__ tyl,
                                                 const float* __restrict__ W,
                                                 const float* __restrict__ bias,
                                                 u16* __restrict__ ohi,
                                                 u16* __restrict__ olo) {
    __shared__ u16 Ah[16 * LSTR], Al[16 * LSTR];
    const int tid = threadIdx.x, wid = tid >> 6, lane = tid & 63;
    const int lrow = lane & 15, lk8 = (lane >> 4) * 8;
    const int col = wid * 16 + lrow;

    bf16x8 wh[6], wl[6];
#pragma unroll
    for (int c = 0; c < 6; ++c) {
        bf16x8 h, l;
#pragma unroll
        for (int i = 0; i < 8; ++i) {
            float wv = foldW(W, c * 32 + lk8 + i, col, 64);
            u16 hb_ = f2bf(wv);
            h[i] = (short)hb_;
            l[i] = (short)f2bf(wv - bf2f(hb_));
        }
        wh[c] = h; wl[c] = l;
    }
    float bv = bias[col];
    const int srow = tid >> 4, sc4 = (tid & 15) * 4;

    for (int t = 0; t < DNT; ++t) {
        int r0 = (blockIdx.x * DNT + t) * 16;
        size_t rb = ((size_t)(r0 + srow) << 6) + sc4;
        {
            float4 v = *(const float4*)&x[rb];
            const float* vp = (const float*)&v;
            ushort4 hv, lv;
#pragma unroll
            for (int i = 0; i < 4; ++i) {
                u16 hb_ = f2bf(vp[i]);
                ((u16*)&hv)[i] = hb_;
                ((u16*)&lv)[i] = f2bf(vp[i] - bf2f(hb_));
            }
            *(ushort4*)&Ah[srow * LSTR + sc4] = hv;
            *(ushort4*)&Al[srow * LSTR + sc4] = lv;
        }
        *(ushort4*)&Ah[srow * LSTR + 64 + sc4] = *(const ushort4*)&a1h[rb];
        *(ushort4*)&Al[srow * LSTR + 64 + sc4] = *(const ushort4*)&a1l[rb];
        *(ushort4*)&Ah[srow * LSTR + 128 + sc4] = *(const ushort4*)&tyh[rb];
        *(ushort4*)&Al[srow * LSTR + 128 + sc4] = *(const ushort4*)&tyl[rb];
        __syncthreads();

        f32x4 acc = {bv, bv, bv, bv};
#pragma unroll
        for (int c = 0; c < 6; ++c) {
            bf16x8 ah = *(const bf16x8*)&Ah[lrow * LSTR + c * 32 + lk8];
            bf16x8 al = *(const bf16x8*)&Al[lrow * LSTR + c * 32 + lk8];
            acc = __builtin_amdgcn_mfma_f32_16x16x32_bf16(ah, wh[c], acc, 0, 0, 0);
            acc = __builtin_amdgcn_mfma_f32_16x16x32_bf16(al, wh[c], acc, 0, 0, 0);
            acc = __builtin_amdgcn_mfma_f32_16x16x32_bf16(ah, wl[c], acc, 0, 0, 0);
        }
        __syncthreads();

#pragma unroll
        for (int j = 0; j < 4; ++j) {
            int row = r0 + (lane >> 4) * 4 + j;
            float v = fmaxf(acc[j], 0.0f);
            u16 hb_ = f2bf(v);
            ohi[((size_t)row << 6) + col] = hb_;
            olo[((size_t)row << 6) + col] = f2bf(v - bf2f(hb_));
        }
    }
}

__global__ __launch_bounds__(256) void dense2_mf(const u16* __restrict__ a0h,
                                                 const u16* __restrict__ a0l,
                                                 const u16* __restrict__ a1h,
                                                 const u16* __restrict__ a1l,
                                                 const u16* __restrict__ tyh,
                                                 const u16* __restrict__ tyl,
                                                 const float* __restrict__ W,
                                                 const float* __restrict__ bias,
                                                 float* __restrict__ out) {
    __shared__ u16 Ah[16 * LSTR], Al[16 * LSTR];
    __shared__ float Ls[16][48];
    const int tid = threadIdx.x, wid = tid >> 6, lane = tid & 63;
    const int lrow = lane & 15, lk8 = (lane >> 4) * 8;
    const int col = wid * 16 + lrow;
    const bool act = (wid < 3);
    const bool cok = act && (col < NCLS);

    bf16x8 wh[6], wl[6];
#pragma unroll
    for (int c = 0; c < 6; ++c) {
        bf16x8 h = 0, l = 0;
        if (cok) {
#pragma unroll
            for (int i = 0; i < 8; ++i) {
                float wv = foldW(W, c * 32 + lk8 + i, col, NCLS);
                u16 hb_ = f2bf(wv);
                h[i] = (short)hb_;
                l[i] = (short)f2bf(wv - bf2f(hb_));
            }
        }
        wh[c] = h; wl[c] = l;
    }
    float bv = cok ? bias[col] : 0.0f;
    const int srow = tid >> 4, sc4 = (tid & 15) * 4;

    for (int t = 0; t < DNT; ++t) {
        int r0 = (blockIdx.x * DNT + t) * 16;
        size_t rb = ((size_t)(r0 + srow) << 6) + sc4;
        *(ushort4*)&Ah[srow * LSTR + sc4] = *(const ushort4*)&a0h[rb];
        *(ushort4*)&Al[srow * LSTR + sc4] = *(const ushort4*)&a0l[rb];
        *(ushort4*)&Ah[srow * LSTR + 64 + sc4] = *(const ushort4*)&a1h[rb];
        *(ushort4*)&Al[srow * LSTR + 64 + sc4] = *(const ushort4*)&a1l[rb];
        *(ushort4*)&Ah[srow * LSTR + 128 + sc4] = *(const ushort4*)&tyh[rb];
        *(ushort4*)&Al[srow * LSTR + 128 + sc4] = *(const ushort4*)&tyl[rb];
        __syncthreads();

        if (act) {
            f32x4 acc = {bv, bv, bv, bv};
#pragma unroll
            for (int c = 0; c < 6; ++c) {
                bf16x8 ah = *(const bf16x8*)&Ah[lrow * LSTR + c * 32 + lk8];
                bf16x8 al = *(const bf16x8*)&Al[lrow * LSTR + c * 32 + lk8];
                acc = __builtin_amdgcn_mfma_f32_16x16x32_bf16(ah, wh[c], acc, 0, 0, 0);
                acc = __builtin_amdgcn_mfma_f32_16x16x32_bf16(al, wh[c], acc, 0, 0, 0);
                acc = __builtin_amdgcn_mfma_f32_16x16x32_bf16(ah, wl[c], acc, 0, 0, 0);
            }
#pragma unroll
            for (int j = 0; j < 4; ++j) Ls[(lane >> 4) * 4 + j][col] = acc[j];
        }
        __syncthreads();

        {   // softmax: 16 rows, one 16-lane group per row (4 rows per wave)
            int row = wid * 4 + (lane >> 4);
            int cg = lane & 15;
            float v0 = Ls[row][cg];
            float v1 = Ls[row][cg + 16];
            float v2 = (cg < 8) ? Ls[row][cg + 32] : -1e30f;
            float m = fmaxf(fmaxf(v0, v1), v2);
#pragma unroll
            for (int o = 8; o; o >>= 1) m = fmaxf(m, __shfl_xor(m, o));
            float e0 = expf(v0 - m), e1 = expf(v1 - m);
            float e2 = (cg < 8) ? expf(v2 - m) : 0.0f;
            float s = e0 + e1 + e2;
#pragma unroll
            for (int o = 8; o; o >>= 1) s += __shfl_xor(s, o);
            float inv = 1.0f / s;
            size_t ob = (size_t)(r0 + row) * NCLS;
            out[ob + cg] = e0 * inv;
            out[ob + cg + 16] = e1 * inv;
            if (cg < 8) out[ob + cg + 32] = e2 * inv;
        }
    }
}

// ---------------- host ----------------

extern "C" void kernel_launch(void* const* d_in, const int* in_sizes, int n_in,
                              void* d_out, int out_size, void* d_ws, size_t ws_size,
                              hipStream_t stream) {
    const float* x = (const float*)d_in[0];
    const int* edge_index = (const int*)d_in[1];
    const float* W1 = (const float*)d_in[2];
    const float* b1 = (const float*)d_in[3];
    const float* W2 = (const float*)d_in[4];
    const float* b2 = (const float*)d_in[5];
    float* out = (float*)d_out;

    const int* src = edge_index;
    const int* dst = edge_index + N_EDGES;

    char* ws = (char*)d_ws;
    size_t off = 0;
    auto carve = [&](size_t bytes) -> void* {
        void* p = ws + off;
        off = align256(off + bytes);
        return p;
    };
    int* gFillD = (int*)carve((size_t)NBUCK * 4);
    int* gFillS = (int*)carve((size_t)NBUCK * 4);
    size_t zero_bytes = off;
    u32* partD = (u32*)carve((size_t)NBUCK * CAPE * 4);     // 7.0 MB ((s<<9)|dlocal)
    int* partS = (int*)carve((size_t)NBUCK * CAPE * 4);     // 7.0 MB
    u32* csr = (u32*)carve((size_t)NBUCK * CAPC * 4 + 1024);// 8.4 MB (src|w15<<17)
    int2* meta = (int2*)carve((size_t)N_NODES * 8);         // 0.8 MB
    float* dis = (float*)carve((size_t)(N_NODES + 1) * 4);  // 0.4 MB (+DUMMY)
    const size_t FB = (size_t)(N_NODES + 1) * 64 * 2;       // 12.8 MB per bf16 plane (+DUMMY row)
    u16* xb  = (u16*)carve(FB);
    u16* t1h = (u16*)carve(FB);   // Tx1 / Th1 hi
    u16* t1l = (u16*)carve(FB);   // Tx1 / Th1 lo
    u16* tyh = (u16*)carve(FB);   // L.Tx1 / L.Th1 hi
    u16* tyl = (u16*)carve(FB);   // L.Tx1 / L.Th1 lo
    u16* hh  = (u16*)carve(FB);   // h hi (gather input for layer 2)
    u16* hl  = (u16*)carve(FB);   // h lo
    // total ~113 MB

    const int WV = (N_NODES * 64) / 256;    // 25000 (one wave per node)

    hipMemsetAsync(d_ws, 0, zero_bytes, stream);
    hipMemsetAsync(dis + N_NODES, 0, 4, stream);               // dis[DUMMY] = 0
    hipMemsetAsync(xb + (size_t)N_NODES * 64, 0, 128, stream); // zero DUMMY rows of
    hipMemsetAsync(t1h + (size_t)N_NODES * 64, 0, 128, stream);//   all gather inputs
    hipMemsetAsync(hh + (size_t)N_NODES * 64, 0, 128, stream);

    pscatter_conv<<<PS_BLOCKS + CONV_BLOCKS, 256, 0, stream>>>(src, dst, gFillD, gFillS,
                                                               partD, partS, x, xb);
    build_dis<<<NBUCK, 256, 0, stream>>>(partS, gFillS, dis);
    build_csr<<<NBUCK, 256, 0, stream>>>(partD, gFillD, dis, csr, meta);

    // layer 1: Tx1 = L.x ; Ty = L.Tx1 ; h = relu(x@(W0-W2) + Tx1@W1 + Ty@2W2 + b1)
    spmm<<<WV, 256, 0, stream>>>(xb, dis, meta, csr, t1h, t1l);
    spmm<<<WV, 256, 0, stream>>>(t1h, dis, meta, csr, tyh, tyl);
    dense1_mf<<<DGRID, 256, 0, stream>>>(x, t1h, t1l, tyh, tyl, W1, b1, hh, hl);

    // layer 2 (t1/ty planes reused)
    spmm<<<WV, 256, 0, stream>>>(hh, dis, meta, csr, t1h, t1l);
    spmm<<<WV, 256, 0, stream>>>(t1h, dis, meta, csr, tyh, tyl);
    dense2_mf<<<DGRID, 256, 0, stream>>>(hh, hl, t1h, t1l, tyh, tyl, W2, b2, out);
}

// Round 12
// 270.585 us; speedup vs baseline: 1.0227x; 1.0227x over previous
//
#include <hip/hip_runtime.h>
#include <hip/hip_fp16.h>

#define N_NODES 100000
#define N_EDGES 1600000
#define NCLS 40
#define NBUCK 196          // buckets of 512 nodes; bucket = id >> 9
#define CAPE 8960          // per-bucket edge capacity
#define CAPC 10752         // per-bucket CSR capacity incl. x8 padding
#define DUMMY N_NODES      // pad source id; row DUMMY zeroed, packed w = 0

typedef unsigned short u16;
typedef unsigned int u32;
typedef short bf16x8 __attribute__((ext_vector_type(8)));
typedef float f32x4 __attribute__((ext_vector_type(4)));

static inline size_t align256(size_t x) { return (x + 255) & ~(size_t)255; }

__device__ __forceinline__ float bf2f(u16 h) { return __uint_as_float(((u32)h) << 16); }
__device__ __forceinline__ u16 f2bf(float f) {
    u32 u = __float_as_uint(f);
    u += 0x7FFFu + ((u >> 16) & 1u);  // round-to-nearest-even
    return (u16)(u >> 16);
}
__device__ __forceinline__ u32 pk2(u16 a, u16 b) { return (u32)a | ((u32)b << 16); }
__device__ __forceinline__ u32 pack15(float f) {   // positive fp16 sans sign bit
    return ((u32)__half_as_ushort(__float2half(f))) & 0x7FFFu;
}
__device__ __forceinline__ float unpack15(u32 bits) {
    return __half2float(__ushort_as_half((u16)bits));
}
// de-interleave permutation: rank r -> slot, so half-wave h reads slots [16b+8h, 16b+8h+8)
__device__ __forceinline__ int perm16(int r, int c8) {
    int base16 = (c8 >> 4) << 4;     // full 16-blocks
    if (r < base16) {
        int b = r >> 4, w = r & 15;
        return (b << 4) + ((w & 1) << 3) + (w >> 1);
    }
    int w = r - base16;              // trailing 8-block
    return base16 + ((w & 1) << 2) + (w >> 1);
}

// ---------- pass 1: LDS-histogram partition by bucket + fused x->bf16 ----------
#define PS_BLOCKS 391
#define CONV_BLOCKS 6250

__global__ __launch_bounds__(256) void pscatter_conv(const int* __restrict__ src,
                                                     const int* __restrict__ dst,
                                                     int* __restrict__ gFillD,
                                                     int* __restrict__ gFillS,
                                                     u32* __restrict__ partD,
                                                     int* __restrict__ partS,
                                                     const float* __restrict__ x,
                                                     u16* __restrict__ xb) {
    if (blockIdx.x >= PS_BLOCKS) {
        int i = (blockIdx.x - PS_BLOCKS) * 256 + threadIdx.x;  // 4 floats/thread
        float4 v = *(const float4*)(x + (size_t)i * 4);
        ushort4 o;
        o.x = f2bf(v.x); o.y = f2bf(v.y); o.z = f2bf(v.z); o.w = f2bf(v.w);
        *(ushort4*)(xb + (size_t)i * 4) = o;
        return;
    }
    __shared__ int histD[NBUCK], histS[NBUCK], chunkD[NBUCK], chunkS[NBUCK];
    int tid = threadIdx.x;
    int base = blockIdx.x * 4096;

    int4 sv[4], dv[4];
#pragma unroll
    for (int j = 0; j < 4; ++j) {
        int idx = base + j * 1024 + tid * 4;
        if (idx < N_EDGES) {
            sv[j] = *(const int4*)(src + idx);
            dv[j] = *(const int4*)(dst + idx);
        } else {
            sv[j] = make_int4(0, 0, 0, 0);
            dv[j] = make_int4(0, 0, 0, 0);
        }
    }

    for (int i = tid; i < NBUCK; i += 256) { histD[i] = 0; histS[i] = 0; }
    __syncthreads();
#pragma unroll
    for (int j = 0; j < 4; ++j)
#pragma unroll
        for (int k = 0; k < 4; ++k) {
            int s = ((const int*)&sv[j])[k], d = ((const int*)&dv[j])[k];
            if (s != d) {
                atomicAdd(&histD[d >> 9], 1);
                atomicAdd(&histS[s >> 9], 1);
            }
        }
    __syncthreads();
    for (int B = tid; B < NBUCK; B += 256) {
        int cD = histD[B];
        chunkD[B] = cD ? atomicAdd(&gFillD[B], cD) : 0;
        int cS = histS[B];
        chunkS[B] = cS ? atomicAdd(&gFillS[B], cS) : 0;
    }
    __syncthreads();
    for (int i = tid; i < NBUCK; i += 256) { histD[i] = 0; histS[i] = 0; }
    __syncthreads();
#pragma unroll
    for (int j = 0; j < 4; ++j)
#pragma unroll
        for (int k = 0; k < 4; ++k) {
            int s = ((const int*)&sv[j])[k], d = ((const int*)&dv[j])[k];
            if (s != d) {
                int bD = d >> 9;
                int r = atomicAdd(&histD[bD], 1);
                int o = chunkD[bD] + r;
                if (o < CAPE) partD[bD * CAPE + o] = ((u32)s << 9) | (u32)(d & 511);
                int bS = s >> 9;
                int r2 = atomicAdd(&histS[bS], 1);
                int o2 = chunkS[bS] + r2;
                if (o2 < CAPE) partS[bS * CAPE + o2] = s;
            }
        }
}

// ---------- pass 2a: src-side out-degree histogram -> dis ----------
__global__ __launch_bounds__(256) void build_dis(const int* __restrict__ partS,
                                                 const int* __restrict__ gFillS,
                                                 float* __restrict__ dis) {
    __shared__ int cnt[512];
    int tid = threadIdx.x;
    int B = blockIdx.x;
    for (int i = tid; i < 512; i += 256) cnt[i] = 0;
    __syncthreads();
    int nS = min(gFillS[B], CAPE);
    for (int i = tid; i < nS; i += 256) atomicAdd(&cnt[partS[B * CAPE + i] & 511], 1);
    __syncthreads();
    for (int n = tid; n < 512; n += 256) {
        int node = B * 512 + n;
        if (node < N_NODES) {
            int dg = cnt[n];
            dis[node] = dg > 0 ? 1.0f / sqrtf((float)dg) : 0.0f;
        }
    }
}

// ---------- pass 2b: CSR build, de-interleaved slots, entry = src | fp15(dis[src])<<17 ----------
__global__ __launch_bounds__(256) void build_csr(const u32* __restrict__ partD,
                                                 const int* __restrict__ gFillD,
                                                 const float* __restrict__ dis,
                                                 u32* __restrict__ csr,
                                                 int2* __restrict__ meta) {
    __shared__ int cnt[512], loc[512], rnk[512];
    int tid = threadIdx.x;
    int B = blockIdx.x;
    for (int i = tid; i < 512; i += 256) { cnt[i] = 0; rnk[i] = 0; }
    __syncthreads();
    int nD = min(gFillD[B], CAPE);
    for (int i = tid; i < nD; i += 256) atomicAdd(&cnt[partD[B * CAPE + i] & 511], 1);
    __syncthreads();
    if (tid < 64) {
        int bb = tid * 8, c8[8], mysum = 0;
#pragma unroll
        for (int j = 0; j < 8; ++j) { c8[j] = (cnt[bb + j] + 7) & ~7; mysum += c8[j]; }
        int incl = mysum;
#pragma unroll
        for (int off = 1; off < 64; off <<= 1) {
            int v = __shfl_up(incl, off);
            if (tid >= off) incl += v;
        }
        int run = incl - mysum;
#pragma unroll
        for (int j = 0; j < 8; ++j) { loc[bb + j] = run; run += c8[j]; }
    }
    __syncthreads();
    for (int n = tid; n < 512; n += 256) {
        int node = B * 512 + n;
        if (node < N_NODES) {
            int c = cnt[n], c8 = (c + 7) & ~7;
            meta[node] = make_int2(B * CAPC + loc[n], c);
            for (int e = c; e < c8; ++e)          // DUMMY pads through the same permutation
                csr[B * CAPC + loc[n] + perm16(e, c8)] = (u32)DUMMY;
        }
    }
    for (int i = tid; i < nD; i += 256) {
        u32 p = partD[B * CAPE + i];
        int ln = p & 511;
        u32 s = p >> 9;
        int r = atomicAdd(&rnk[ln], 1);
        int c8 = (cnt[ln] + 7) & ~7;
        int pos = loc[ln] + perm16(r, c8);
        if (pos < CAPC) csr[B * CAPC + pos] = s | (pack15(dis[s]) << 17);
    }
}

// ---------- SPMM pair-gather, packed weights, de-interleaved halves ----------
// half h reads its own 8 entries per 16-edge block (no cndmask); each lane: 2 features.
__global__ __launch_bounds__(256) void spmm(const u16* __restrict__ in,     // (N+1)x64 bf16
                                            const float* __restrict__ dis,
                                            const int2* __restrict__ meta,
                                            const u32* __restrict__ csr,
                                            u16* __restrict__ outhi,
                                            u16* __restrict__ outlo) {
    int node = (blockIdx.x * 256 + threadIdx.x) >> 6;
    int lane = threadIdx.x & 63;
    if (node >= N_NODES) return;
    int2 mt = meta[node];
    int c8 = (mt.y + 7) & ~7;          // lists DUMMY-padded to x8
    const u32* lst = csr + mt.x;       // 32B-aligned
    const u32* in32 = (const u32*)in;
    const int hsel = lane >> 5;
    const int fl = lane & 31;
    float acc0 = 0.0f, acc1 = 0.0f;
    int e = 0;
    for (; e + 16 <= c8; e += 16) {
        const u32* half = lst + e + (hsel << 3);
        uint4 ea = *(const uint4*)half;
        uint4 eb = *(const uint4*)(half + 4);
        u32 e0 = ea.x, e1 = ea.y, e2 = ea.z, e3 = ea.w;
        u32 e4 = eb.x, e5 = eb.y, e6 = eb.z, e7 = eb.w;
        u32 v0 = in32[((e0 & 0x1FFFFu) << 5) + fl];
        u32 v1 = in32[((e1 & 0x1FFFFu) << 5) + fl];
        u32 v2 = in32[((e2 & 0x1FFFFu) << 5) + fl];
        u32 v3 = in32[((e3 & 0x1FFFFu) << 5) + fl];
        u32 v4 = in32[((e4 & 0x1FFFFu) << 5) + fl];
        u32 v5 = in32[((e5 & 0x1FFFFu) << 5) + fl];
        u32 v6 = in32[((e6 & 0x1FFFFu) << 5) + fl];
        u32 v7 = in32[((e7 & 0x1FFFFu) << 5) + fl];
        float w0 = unpack15(e0 >> 17), w1 = unpack15(e1 >> 17);
        float w2 = unpack15(e2 >> 17), w3 = unpack15(e3 >> 17);
        float w4 = unpack15(e4 >> 17), w5 = unpack15(e5 >> 17);
        float w6 = unpack15(e6 >> 17), w7 = unpack15(e7 >> 17);
        acc0 = fmaf(w0, __uint_as_float(v0 << 16), acc0);
        acc1 = fmaf(w0, __uint_as_float(v0 & 0xFFFF0000u), acc1);
        acc0 = fmaf(w1, __uint_as_float(v1 << 16), acc0);
        acc1 = fmaf(w1, __uint_as_float(v1 & 0xFFFF0000u), acc1);
        acc0 = fmaf(w2, __uint_as_float(v2 << 16), acc0);
        acc1 = fmaf(w2, __uint_as_float(v2 & 0xFFFF0000u), acc1);
        acc0 = fmaf(w3, __uint_as_float(v3 << 16), acc0);
        acc1 = fmaf(w3, __uint_as_float(v3 & 0xFFFF0000u), acc1);
        acc0 = fmaf(w4, __uint_as_float(v4 << 16), acc0);
        acc1 = fmaf(w4, __uint_as_float(v4 & 0xFFFF0000u), acc1);
        acc0 = fmaf(w5, __uint_as_float(v5 << 16), acc0);
        acc1 = fmaf(w5, __uint_as_float(v5 & 0xFFFF0000u), acc1);
        acc0 = fmaf(w6, __uint_as_float(v6 << 16), acc0);
        acc1 = fmaf(w6, __uint_as_float(v6 & 0xFFFF0000u), acc1);
        acc0 = fmaf(w7, __uint_as_float(v7 << 16), acc0);
        acc1 = fmaf(w7, __uint_as_float(v7 & 0xFFFF0000u), acc1);
    }
    if (e < c8) {                      // remainder: exactly 8 edges, 4 per half
        const u32* half = lst + e + (hsel << 2);
        uint4 ea = *(const uint4*)half;
        u32 e0 = ea.x, e1 = ea.y, e2 = ea.z, e3 = ea.w;
        u32 v0 = in32[((e0 & 0x1FFFFu) << 5) + fl];
        u32 v1 = in32[((e1 & 0x1FFFFu) << 5) + fl];
        u32 v2 = in32[((e2 & 0x1FFFFu) << 5) + fl];
        u32 v3 = in32[((e3 & 0x1FFFFu) << 5) + fl];
        float w0 = unpack15(e0 >> 17), w1 = unpack15(e1 >> 17);
        float w2 = unpack15(e2 >> 17), w3 = unpack15(e3 >> 17);
        acc0 = fmaf(w0, __uint_as_float(v0 << 16), acc0);
        acc1 = fmaf(w0, __uint_as_float(v0 & 0xFFFF0000u), acc1);
        acc0 = fmaf(w1, __uint_as_float(v1 << 16), acc0);
        acc1 = fmaf(w1, __uint_as_float(v1 & 0xFFFF0000u), acc1);
        acc0 = fmaf(w2, __uint_as_float(v2 << 16), acc0);
        acc1 = fmaf(w2, __uint_as_float(v2 & 0xFFFF0000u), acc1);
        acc0 = fmaf(w3, __uint_as_float(v3 << 16), acc0);
        acc1 = fmaf(w3, __uint_as_float(v3 & 0xFFFF0000u), acc1);
    }
    acc0 += __shfl_xor(acc0, 32);
    acc1 += __shfl_xor(acc1, 32);
    float vd = -dis[node];
    float f0 = vd * acc0, f1 = vd * acc1;
    u32 o32 = ((u32)node << 5) + fl;
    u16 h0 = f2bf(f0), h1 = f2bf(f1);
    if (hsel == 0) {
        ((u32*)outhi)[o32] = pk2(h0, h1);
    } else {
        ((u32*)outlo)[o32] = pk2(f2bf(f0 - bf2f(h0)), f2bf(f1 - bf2f(h1)));
    }
}

// ---------- dense via MFMA, split-bf16, Chebyshev fold in the weights ----------
// out = A0@(W0 - W2) + A1@W1 + Ty@(2*W2)   where Ty = L.A1
#define DGRID 1250
#define DNT 5              // 1250 * 5 * 16 = 100000 rows exactly (round-10 proven)
#define LSTR 200           // u16 per LDS row (192 data + 8 pad)

__device__ __forceinline__ float foldW(const float* __restrict__ W, int kk, int col,
                                       int ncols) {
    float wv = W[kk * ncols + col];
    if (kk < 64) wv -= W[(kk + 128) * ncols + col];   // W0 - W2
    else if (kk >= 128) wv += wv;                     // 2 * W2
    return wv;
}

__global__ __launch_bounds__(256) void dense1_mf(const float* __restrict__ x,
                                                 const u16* __restrict__ a1h,
                                                 const u16* __restrict__ a1l,
                                                 const u16* __restrict__ tyh,
                                                 const u16* __restrict__ tyl,
                                                 const float* __restrict__ W,
                                                 const float* __restrict__ bias,
                                                 u16* __restrict__ ohi,
                                                 u16* __restrict__ olo) {
    __shared__ u16 Ah[16 * LSTR], Al[16 * LSTR];
    const int tid = threadIdx.x, wid = tid >> 6, lane = tid & 63;
    const int lrow = lane & 15, lk8 = (lane >> 4) * 8;
    const int col = wid * 16 + lrow;

    bf16x8 wh[6], wl[6];
#pragma unroll
    for (int c = 0; c < 6; ++c) {
        bf16x8 h, l;
#pragma unroll
        for (int i = 0; i < 8; ++i) {
            float wv = foldW(W, c * 32 + lk8 + i, col, 64);
            u16 hb_ = f2bf(wv);
            h[i] = (short)hb_;
            l[i] = (short)f2bf(wv - bf2f(hb_));
        }
        wh[c] = h; wl[c] = l;
    }
    float bv = bias[col];
    const int srow = tid >> 4, sc4 = (tid & 15) * 4;

    for (int t = 0; t < DNT; ++t) {
        int r0 = (blockIdx.x * DNT + t) * 16;
        size_t rb = ((size_t)(r0 + srow) << 6) + sc4;
        {
            float4 v = *(const float4*)&x[rb];
            const float* vp = (const float*)&v;
            ushort4 hv, lv;
#pragma unroll
            for (int i = 0; i < 4; ++i) {
                u16 hb_ = f2bf(vp[i]);
                ((u16*)&hv)[i] = hb_;
                ((u16*)&lv)[i] = f2bf(vp[i] - bf2f(hb_));
            }
            *(ushort4*)&Ah[srow * LSTR + sc4] = hv;
            *(ushort4*)&Al[srow * LSTR + sc4] = lv;
        }
        *(ushort4*)&Ah[srow * LSTR + 64 + sc4] = *(const ushort4*)&a1h[rb];
        *(ushort4*)&Al[srow * LSTR + 64 + sc4] = *(const ushort4*)&a1l[rb];
        *(ushort4*)&Ah[srow * LSTR + 128 + sc4] = *(const ushort4*)&tyh[rb];
        *(ushort4*)&Al[srow * LSTR + 128 + sc4] = *(const ushort4*)&tyl[rb];
        __syncthreads();

        f32x4 acc = {bv, bv, bv, bv};
#pragma unroll
        for (int c = 0; c < 6; ++c) {
            bf16x8 ah = *(const bf16x8*)&Ah[lrow * LSTR + c * 32 + lk8];
            bf16x8 al = *(const bf16x8*)&Al[lrow * LSTR + c * 32 + lk8];
            acc = __builtin_amdgcn_mfma_f32_16x16x32_bf16(ah, wh[c], acc, 0, 0, 0);
            acc = __builtin_amdgcn_mfma_f32_16x16x32_bf16(al, wh[c], acc, 0, 0, 0);
            acc = __builtin_amdgcn_mfma_f32_16x16x32_bf16(ah, wl[c], acc, 0, 0, 0);
        }
        __syncthreads();

#pragma unroll
        for (int j = 0; j < 4; ++j) {
            int row = r0 + (lane >> 4) * 4 + j;
            float v = fmaxf(acc[j], 0.0f);
            u16 hb_ = f2bf(v);
            ohi[((size_t)row << 6) + col] = hb_;
            olo[((size_t)row << 6) + col] = f2bf(v - bf2f(hb_));
        }
    }
}

__global__ __launch_bounds__(256) void dense2_mf(const u16* __restrict__ a0h,
                                                 const u16* __restrict__ a0l,
                                                 const u16* __restrict__ a1h,
                                                 const u16* __restrict__ a1l,
                                                 const u16* __restrict__ tyh,
                                                 const u16* __restrict__ tyl,
                                                 const float* __restrict__ W,
                                                 const float* __restrict__ bias,
                                                 float* __restrict__ out) {
    __shared__ u16 Ah[16 * LSTR], Al[16 * LSTR];
    __shared__ float Ls[16][48];
    const int tid = threadIdx.x, wid = tid >> 6, lane = tid & 63;
    const int lrow = lane & 15, lk8 = (lane >> 4) * 8;
    const int col = wid * 16 + lrow;
    const bool act = (wid < 3);
    const bool cok = act && (col < NCLS);

    bf16x8 wh[6], wl[6];
#pragma unroll
    for (int c = 0; c < 6; ++c) {
        bf16x8 h = 0, l = 0;
        if (cok) {
#pragma unroll
            for (int i = 0; i < 8; ++i) {
                float wv = foldW(W, c * 32 + lk8 + i, col, NCLS);
                u16 hb_ = f2bf(wv);
                h[i] = (short)hb_;
                l[i] = (short)f2bf(wv - bf2f(hb_));
            }
        }
        wh[c] = h; wl[c] = l;
    }
    float bv = cok ? bias[col] : 0.0f;
    const int srow = tid >> 4, sc4 = (tid & 15) * 4;

    for (int t = 0; t < DNT; ++t) {
        int r0 = (blockIdx.x * DNT + t) * 16;
        size_t rb = ((size_t)(r0 + srow) << 6) + sc4;
        *(ushort4*)&Ah[srow * LSTR + sc4] = *(const ushort4*)&a0h[rb];
        *(ushort4*)&Al[srow * LSTR + sc4] = *(const ushort4*)&a0l[rb];
        *(ushort4*)&Ah[srow * LSTR + 64 + sc4] = *(const ushort4*)&a1h[rb];
        *(ushort4*)&Al[srow * LSTR + 64 + sc4] = *(const ushort4*)&a1l[rb];
        *(ushort4*)&Ah[srow * LSTR + 128 + sc4] = *(const ushort4*)&tyh[rb];
        *(ushort4*)&Al[srow * LSTR + 128 + sc4] = *(const ushort4*)&tyl[rb];
        __syncthreads();

        if (act) {
            f32x4 acc = {bv, bv, bv, bv};
#pragma unroll
            for (int c = 0; c < 6; ++c) {
                bf16x8 ah = *(const bf16x8*)&Ah[lrow * LSTR + c * 32 + lk8];
                bf16x8 al = *(const bf16x8*)&Al[lrow * LSTR + c * 32 + lk8];
                acc = __builtin_amdgcn_mfma_f32_16x16x32_bf16(ah, wh[c], acc, 0, 0, 0);
                acc = __builtin_amdgcn_mfma_f32_16x16x32_bf16(al, wh[c], acc, 0, 0, 0);
                acc = __builtin_amdgcn_mfma_f32_16x16x32_bf16(ah, wl[c], acc, 0, 0, 0);
            }
#pragma unroll
            for (int j = 0; j < 4; ++j) Ls[(lane >> 4) * 4 + j][col] = acc[j];
        }
        __syncthreads();

        {   // softmax: 16 rows, one 16-lane group per row (4 rows per wave)
            int row = wid * 4 + (lane >> 4);
            int cg = lane & 15;
            float v0 = Ls[row][cg];
            float v1 = Ls[row][cg + 16];
            float v2 = (cg < 8) ? Ls[row][cg + 32] : -1e30f;
            float m = fmaxf(fmaxf(v0, v1), v2);
#pragma unroll
            for (int o = 8; o; o >>= 1) m = fmaxf(m, __shfl_xor(m, o));
            float e0 = expf(v0 - m), e1 = expf(v1 - m);
            float e2 = (cg < 8) ? expf(v2 - m) : 0.0f;
            float s = e0 + e1 + e2;
#pragma unroll
            for (int o = 8; o; o >>= 1) s += __shfl_xor(s, o);
            float inv = 1.0f / s;
            size_t ob = (size_t)(r0 + row) * NCLS;
            out[ob + cg] = e0 * inv;
            out[ob + cg + 16] = e1 * inv;
            if (cg < 8) out[ob + cg + 32] = e2 * inv;
        }
    }
}

// ---------------- host ----------------

extern "C" void kernel_launch(void* const* d_in, const int* in_sizes, int n_in,
                              void* d_out, int out_size, void* d_ws, size_t ws_size,
                              hipStream_t stream) {
    const float* x = (const float*)d_in[0];
    const int* edge_index = (const int*)d_in[1];
    const float* W1 = (const float*)d_in[2];
    const float* b1 = (const float*)d_in[3];
    const float* W2 = (const float*)d_in[4];
    const float* b2 = (const float*)d_in[5];
    float* out = (float*)d_out;

    const int* src = edge_index;
    const int* dst = edge_index + N_EDGES;

    char* ws = (char*)d_ws;
    size_t off = 0;
    auto carve = [&](size_t bytes) -> void* {
        void* p = ws + off;
        off = align256(off + bytes);
        return p;
    };
    int* gFillD = (int*)carve((size_t)NBUCK * 4);
    int* gFillS = (int*)carve((size_t)NBUCK * 4);
    size_t zero_bytes = off;
    u32* partD = (u32*)carve((size_t)NBUCK * CAPE * 4);     // 7.0 MB ((s<<9)|dlocal)
    int* partS = (int*)carve((size_t)NBUCK * CAPE * 4);     // 7.0 MB
    u32* csr = (u32*)carve((size_t)NBUCK * CAPC * 4 + 1024);// 8.4 MB (src|w15<<17)
    int2* meta = (int2*)carve((size_t)N_NODES * 8);         // 0.8 MB
    float* dis = (float*)carve((size_t)(N_NODES + 1) * 4);  // 0.4 MB (+DUMMY)
    const size_t FB = (size_t)(N_NODES + 1) * 64 * 2;       // 12.8 MB per bf16 plane (+DUMMY row)
    u16* xb  = (u16*)carve(FB);
    u16* t1h = (u16*)carve(FB);   // Tx1 / Th1 hi
    u16* t1l = (u16*)carve(FB);   // Tx1 / Th1 lo
    u16* tyh = (u16*)carve(FB);   // L.Tx1 / L.Th1 hi
    u16* tyl = (u16*)carve(FB);   // L.Tx1 / L.Th1 lo
    u16* hh  = (u16*)carve(FB);   // h hi (gather input for layer 2)
    u16* hl  = (u16*)carve(FB);   // h lo
    // total ~113 MB

    const int WV = (N_NODES * 64) / 256;    // 25000 (one wave per node)

    hipMemsetAsync(d_ws, 0, zero_bytes, stream);
    hipMemsetAsync(dis + N_NODES, 0, 4, stream);               // dis[DUMMY] = 0
    hipMemsetAsync(xb + (size_t)N_NODES * 64, 0, 128, stream); // zero DUMMY rows of
    hipMemsetAsync(t1h + (size_t)N_NODES * 64, 0, 128, stream);//   all gather inputs
    hipMemsetAsync(hh + (size_t)N_NODES * 64, 0, 128, stream);

    pscatter_conv<<<PS_BLOCKS + CONV_BLOCKS, 256, 0, stream>>>(src, dst, gFillD, gFillS,
                                                               partD, partS, x, xb);
    build_dis<<<NBUCK, 256, 0, stream>>>(partS, gFillS, dis);
    build_csr<<<NBUCK, 256, 0, stream>>>(partD, gFillD, dis, csr, meta);

    // layer 1: Tx1 = L.x ; Ty = L.Tx1 ; h = relu(x@(W0-W2) + Tx1@W1 + Ty@2W2 + b1)
    spmm<<<WV, 256, 0, stream>>>(xb, dis, meta, csr, t1h, t1l);
    spmm<<<WV, 256, 0, stream>>>(t1h, dis, meta, csr, tyh, tyl);
    dense1_mf<<<DGRID, 256, 0, stream>>>(x, t1h, t1l, tyh, tyl, W1, b1, hh, hl);

    // layer 2 (t1/ty planes reused)
    spmm<<<WV, 256, 0, stream>>>(hh, dis, meta, csr, t1h, t1l);
    spmm<<<WV, 256, 0, stream>>>(t1h, dis, meta, csr, tyh, tyl);
    dense2_mf<<<DGRID, 256, 0, stream>>>(hh, hl, t1h, t1l, tyh, tyl, W2, b2, out);
}

// Round 13
// 249.600 us; speedup vs baseline: 1.1087x; 1.0841x over previous
//
#include <hip/hip_runtime.h>
#include <hip/hip_fp16.h>

#define N_NODES 100000
#define N_EDGES 1600000
#define NCLS 40
#define NBUCK 196          // buckets of 512 nodes; bucket = id >> 9
#define CAPE 8960          // per-bucket edge capacity
#define CAPC 10752         // per-bucket CSR capacity incl. x8 padding
#define DUMMY N_NODES      // pad source id; packed w bits = 0 -> exact no-op

typedef unsigned short u16;
typedef unsigned int u32;
typedef short bf16x8 __attribute__((ext_vector_type(8)));
typedef float f32x4 __attribute__((ext_vector_type(4)));

static inline size_t align256(size_t x) { return (x + 255) & ~(size_t)255; }

__device__ __forceinline__ float bf2f(u16 h) { return __uint_as_float(((u32)h) << 16); }
__device__ __forceinline__ u16 f2bf(float f) {
    u32 u = __float_as_uint(f);
    u += 0x7FFFu + ((u >> 16) & 1u);  // round-to-nearest-even
    return (u16)(u >> 16);
}
__device__ __forceinline__ u32 pk2(u16 a, u16 b) { return (u32)a | ((u32)b << 16); }
__device__ __forceinline__ u32 pack15(float f) {   // positive fp16 sans sign bit
    return ((u32)__half_as_ushort(__float2half(f))) & 0x7FFFu;
}
__device__ __forceinline__ float unpack15(u32 bits) {
    return __half2float(__ushort_as_half((u16)bits));
}
// de-interleave permutation: rank r -> slot, so half-wave h reads slots [16b+8h, 16b+8h+8)
__device__ __forceinline__ int perm16(int r, int c8) {
    int base16 = (c8 >> 4) << 4;     // full 16-blocks
    if (r < base16) {
        int b = r >> 4, w = r & 15;
        return (b << 4) + ((w & 1) << 3) + (w >> 1);
    }
    int w = r - base16;              // trailing 8-block
    return base16 + ((w & 1) << 2) + (w >> 1);
}

// ---------- pass 1: LDS-histogram partition by bucket + fused x->bf16 ----------
#define PS_BLOCKS 391
#define CONV_BLOCKS 6250

__global__ __launch_bounds__(256) void pscatter_conv(const int* __restrict__ src,
                                                     const int* __restrict__ dst,
                                                     int* __restrict__ gFillD,
                                                     int* __restrict__ gFillS,
                                                     u32* __restrict__ partD,
                                                     u16* __restrict__ partS,
                                                     const float* __restrict__ x,
                                                     u16* __restrict__ xb) {
    if (blockIdx.x >= PS_BLOCKS) {
        int i = (blockIdx.x - PS_BLOCKS) * 256 + threadIdx.x;  // 4 floats/thread
        float4 v = *(const float4*)(x + (size_t)i * 4);
        ushort4 o;
        o.x = f2bf(v.x); o.y = f2bf(v.y); o.z = f2bf(v.z); o.w = f2bf(v.w);
        *(ushort4*)(xb + (size_t)i * 4) = o;
        return;
    }
    __shared__ int histD[NBUCK], histS[NBUCK], chunkD[NBUCK], chunkS[NBUCK];
    int tid = threadIdx.x;
    int base = blockIdx.x * 4096;

    int4 sv[4], dv[4];
#pragma unroll
    for (int j = 0; j < 4; ++j) {
        int idx = base + j * 1024 + tid * 4;
        if (idx < N_EDGES) {
            sv[j] = *(const int4*)(src + idx);
            dv[j] = *(const int4*)(dst + idx);
        } else {
            sv[j] = make_int4(0, 0, 0, 0);
            dv[j] = make_int4(0, 0, 0, 0);
        }
    }

    for (int i = tid; i < NBUCK; i += 256) { histD[i] = 0; histS[i] = 0; }
    __syncthreads();
#pragma unroll
    for (int j = 0; j < 4; ++j)
#pragma unroll
        for (int k = 0; k < 4; ++k) {
            int s = ((const int*)&sv[j])[k], d = ((const int*)&dv[j])[k];
            if (s != d) {
                atomicAdd(&histD[d >> 9], 1);
                atomicAdd(&histS[s >> 9], 1);
            }
        }
    __syncthreads();
    for (int B = tid; B < NBUCK; B += 256) {
        int cD = histD[B];
        chunkD[B] = cD ? atomicAdd(&gFillD[B], cD) : 0;
        int cS = histS[B];
        chunkS[B] = cS ? atomicAdd(&gFillS[B], cS) : 0;
    }
    __syncthreads();
    for (int i = tid; i < NBUCK; i += 256) { histD[i] = 0; histS[i] = 0; }
    __syncthreads();
#pragma unroll
    for (int j = 0; j < 4; ++j)
#pragma unroll
        for (int k = 0; k < 4; ++k) {
            int s = ((const int*)&sv[j])[k], d = ((const int*)&dv[j])[k];
            if (s != d) {
                int bD = d >> 9;
                int r = atomicAdd(&histD[bD], 1);
                int o = chunkD[bD] + r;
                if (o < CAPE) partD[bD * CAPE + o] = ((u32)s << 9) | (u32)(d & 511);
                int bS = s >> 9;
                int r2 = atomicAdd(&histS[bS], 1);
                int o2 = chunkS[bS] + r2;
                if (o2 < CAPE) partS[bS * CAPE + o2] = (u16)(s & 511);
            }
        }
}

// ---------- pass 2a: src-side out-degree histogram -> dis ----------
__global__ __launch_bounds__(256) void build_dis(const u16* __restrict__ partS,
                                                 const int* __restrict__ gFillS,
                                                 float* __restrict__ dis) {
    __shared__ int cnt[512];
    int tid = threadIdx.x;
    int B = blockIdx.x;
    for (int i = tid; i < 512; i += 256) cnt[i] = 0;
    __syncthreads();
    int nS = min(gFillS[B], CAPE);
    for (int i = tid; i < nS; i += 256) atomicAdd(&cnt[partS[B * CAPE + i]], 1);
    __syncthreads();
    for (int n = tid; n < 512; n += 256) {
        int node = B * 512 + n;
        if (node < N_NODES) {
            int dg = cnt[n];
            dis[node] = dg > 0 ? 1.0f / sqrtf((float)dg) : 0.0f;
        }
    }
}

// ---------- pass 2b: CSR build, de-interleaved slots, entry = src | fp15(dis[src])<<17 ----------
__global__ __launch_bounds__(256) void build_csr(const u32* __restrict__ partD,
                                                 const int* __restrict__ gFillD,
                                                 const float* __restrict__ dis,
                                                 u32* __restrict__ csr,
                                                 int2* __restrict__ meta) {
    __shared__ int cnt[512], loc[512], rnk[512];
    int tid = threadIdx.x;
    int B = blockIdx.x;
    for (int i = tid; i < 512; i += 256) { cnt[i] = 0; rnk[i] = 0; }
    __syncthreads();
    int nD = min(gFillD[B], CAPE);
    for (int i = tid; i < nD; i += 256) atomicAdd(&cnt[partD[B * CAPE + i] & 511], 1);
    __syncthreads();
    if (tid < 64) {
        int bb = tid * 8, c8[8], mysum = 0;
#pragma unroll
        for (int j = 0; j < 8; ++j) { c8[j] = (cnt[bb + j] + 7) & ~7; mysum += c8[j]; }
        int incl = mysum;
#pragma unroll
        for (int off = 1; off < 64; off <<= 1) {
            int v = __shfl_up(incl, off);
            if (tid >= off) incl += v;
        }
        int run = incl - mysum;
#pragma unroll
        for (int j = 0; j < 8; ++j) { loc[bb + j] = run; run += c8[j]; }
    }
    __syncthreads();
    for (int n = tid; n < 512; n += 256) {
        int node = B * 512 + n;
        if (node < N_NODES) {
            int c = cnt[n], c8 = (c + 7) & ~7;
            meta[node] = make_int2(B * CAPC + loc[n], c);
            for (int e = c; e < c8; ++e)          // DUMMY pads through the same permutation
                csr[B * CAPC + loc[n] + perm16(e, c8)] = (u32)DUMMY;
        }
    }
    for (int i = tid; i < nD; i += 256) {
        u32 p = partD[B * CAPE + i];
        int ln = p & 511;
        u32 s = p >> 9;
        int r = atomicAdd(&rnk[ln], 1);
        int c8 = (cnt[ln] + 7) & ~7;
        int pos = loc[ln] + perm16(r, c8);
        if (pos < CAPC) csr[B * CAPC + pos] = s | (pack15(dis[s]) << 17);
    }
}

// ---------- SPMM pair-gather, packed weights, de-interleaved halves ----------
// half h reads its own 8 entries per 16-edge block (no cndmask); each lane: 2 features.
__global__ __launch_bounds__(256) void spmm(const u16* __restrict__ in,     // (N+1)x64 bf16
                                            const float* __restrict__ dis,
                                            const int2* __restrict__ meta,
                                            const u32* __restrict__ csr,
                                            u16* __restrict__ outhi,
                                            u16* __restrict__ outlo) {
    int node = (blockIdx.x * 256 + threadIdx.x) >> 6;
    int lane = threadIdx.x & 63;
    if (node >= N_NODES) return;
    node = __builtin_amdgcn_readfirstlane(node);   // wave-uniform -> scalar loads
    int2 mt = meta[node];
    int c8 = (mt.y + 7) & ~7;          // lists DUMMY-padded to x8
    const u32* lst = csr + mt.x;       // 32B-aligned
    const u32* in32 = (const u32*)in;
    const int hsel = lane >> 5;
    const int fl = lane & 31;
    float acc0 = 0.0f, acc1 = 0.0f;
    int e = 0;
    for (; e + 16 <= c8; e += 16) {
        const u32* half = lst + e + (hsel << 3);
        uint4 ea = *(const uint4*)half;
        uint4 eb = *(const uint4*)(half + 4);
        u32 e0 = ea.x, e1 = ea.y, e2 = ea.z, e3 = ea.w;
        u32 e4 = eb.x, e5 = eb.y, e6 = eb.z, e7 = eb.w;
        u32 v0 = in32[((e0 & 0x1FFFFu) << 5) + fl];
        u32 v1 = in32[((e1 & 0x1FFFFu) << 5) + fl];
        u32 v2 = in32[((e2 & 0x1FFFFu) << 5) + fl];
        u32 v3 = in32[((e3 & 0x1FFFFu) << 5) + fl];
        u32 v4 = in32[((e4 & 0x1FFFFu) << 5) + fl];
        u32 v5 = in32[((e5 & 0x1FFFFu) << 5) + fl];
        u32 v6 = in32[((e6 & 0x1FFFFu) << 5) + fl];
        u32 v7 = in32[((e7 & 0x1FFFFu) << 5) + fl];
        float w0 = unpack15(e0 >> 17), w1 = unpack15(e1 >> 17);
        float w2 = unpack15(e2 >> 17), w3 = unpack15(e3 >> 17);
        float w4 = unpack15(e4 >> 17), w5 = unpack15(e5 >> 17);
        float w6 = unpack15(e6 >> 17), w7 = unpack15(e7 >> 17);
        acc0 = fmaf(w0, __uint_as_float(v0 << 16), acc0);
        acc1 = fmaf(w0, __uint_as_float(v0 & 0xFFFF0000u), acc1);
        acc0 = fmaf(w1, __uint_as_float(v1 << 16), acc0);
        acc1 = fmaf(w1, __uint_as_float(v1 & 0xFFFF0000u), acc1);
        acc0 = fmaf(w2, __uint_as_float(v2 << 16), acc0);
        acc1 = fmaf(w2, __uint_as_float(v2 & 0xFFFF0000u), acc1);
        acc0 = fmaf(w3, __uint_as_float(v3 << 16), acc0);
        acc1 = fmaf(w3, __uint_as_float(v3 & 0xFFFF0000u), acc1);
        acc0 = fmaf(w4, __uint_as_float(v4 << 16), acc0);
        acc1 = fmaf(w4, __uint_as_float(v4 & 0xFFFF0000u), acc1);
        acc0 = fmaf(w5, __uint_as_float(v5 << 16), acc0);
        acc1 = fmaf(w5, __uint_as_float(v5 & 0xFFFF0000u), acc1);
        acc0 = fmaf(w6, __uint_as_float(v6 << 16), acc0);
        acc1 = fmaf(w6, __uint_as_float(v6 & 0xFFFF0000u), acc1);
        acc0 = fmaf(w7, __uint_as_float(v7 << 16), acc0);
        acc1 = fmaf(w7, __uint_as_float(v7 & 0xFFFF0000u), acc1);
    }
    if (e < c8) {                      // remainder: exactly 8 edges, 4 per half
        const u32* half = lst + e + (hsel << 2);
        uint4 ea = *(const uint4*)half;
        u32 e0 = ea.x, e1 = ea.y, e2 = ea.z, e3 = ea.w;
        u32 v0 = in32[((e0 & 0x1FFFFu) << 5) + fl];
        u32 v1 = in32[((e1 & 0x1FFFFu) << 5) + fl];
        u32 v2 = in32[((e2 & 0x1FFFFu) << 5) + fl];
        u32 v3 = in32[((e3 & 0x1FFFFu) << 5) + fl];
        float w0 = unpack15(e0 >> 17), w1 = unpack15(e1 >> 17);
        float w2 = unpack15(e2 >> 17), w3 = unpack15(e3 >> 17);
        acc0 = fmaf(w0, __uint_as_float(v0 << 16), acc0);
        acc1 = fmaf(w0, __uint_as_float(v0 & 0xFFFF0000u), acc1);
        acc0 = fmaf(w1, __uint_as_float(v1 << 16), acc0);
        acc1 = fmaf(w1, __uint_as_float(v1 & 0xFFFF0000u), acc1);
        acc0 = fmaf(w2, __uint_as_float(v2 << 16), acc0);
        acc1 = fmaf(w2, __uint_as_float(v2 & 0xFFFF0000u), acc1);
        acc0 = fmaf(w3, __uint_as_float(v3 << 16), acc0);
        acc1 = fmaf(w3, __uint_as_float(v3 & 0xFFFF0000u), acc1);
    }
    acc0 += __shfl_xor(acc0, 32);
    acc1 += __shfl_xor(acc1, 32);
    float vd = -dis[node];
    float f0 = vd * acc0, f1 = vd * acc1;
    u32 o32 = ((u32)node << 5) + fl;
    u16 h0 = f2bf(f0), h1 = f2bf(f1);
    if (hsel == 0) {
        ((u32*)outhi)[o32] = pk2(h0, h1);
    } else {
        ((u32*)outlo)[o32] = pk2(f2bf(f0 - bf2f(h0)), f2bf(f1 - bf2f(h1)));
    }
}

// ---------- dense via MFMA, split-bf16, Chebyshev fold in the weights ----------
// out = A0@(W0 - W2) + A1@W1 + Ty@(2*W2)   where Ty = L.A1
#define DGRID 1250
#define DNT 5              // 1250 * 5 * 16 = 100000 rows exactly (round-10 proven)
#define LSTR 200           // u16 per LDS row (192 data + 8 pad)

__device__ __forceinline__ float foldW(const float* __restrict__ W, int kk, int col,
                                       int ncols) {
    float wv = W[kk * ncols + col];
    if (kk < 64) wv -= W[(kk + 128) * ncols + col];   // W0 - W2
    else if (kk >= 128) wv += wv;                     // 2 * W2
    return wv;
}

__global__ __launch_bounds__(256) void dense1_mf(const float* __restrict__ x,
                                                 const u16* __restrict__ a1h,
                                                 const u16* __restrict__ a1l,
                                                 const u16* __restrict__ tyh,
                                                 const u16* __restrict__ tyl,
                                                 const float* __restrict__ W,
                                                 const float* __restrict__ bias,
                                                 u16* __restrict__ ohi,
                                                 u16* __restrict__ olo) {
    __shared__ u16 Ah[16 * LSTR], Al[16 * LSTR];
    const int tid = threadIdx.x, wid = tid >> 6, lane = tid & 63;
    const int lrow = lane & 15, lk8 = (lane >> 4) * 8;
    const int col = wid * 16 + lrow;

    bf16x8 wh[6], wl[6];
#pragma unroll
    for (int c = 0; c < 6; ++c) {
        bf16x8 h, l;
#pragma unroll
        for (int i = 0; i < 8; ++i) {
            float wv = foldW(W, c * 32 + lk8 + i, col, 64);
            u16 hb_ = f2bf(wv);
            h[i] = (short)hb_;
            l[i] = (short)f2bf(wv - bf2f(hb_));
        }
        wh[c] = h; wl[c] = l;
    }
    float bv = bias[col];
    const int srow = tid >> 4, sc4 = (tid & 15) * 4;

    for (int t = 0; t < DNT; ++t) {
        int r0 = (blockIdx.x * DNT + t) * 16;
        size_t rb = ((size_t)(r0 + srow) << 6) + sc4;
        {
            float4 v = *(const float4*)&x[rb];
            const float* vp = (const float*)&v;
            ushort4 hv, lv;
#pragma unroll
            for (int i = 0; i < 4; ++i) {
                u16 hb_ = f2bf(vp[i]);
                ((u16*)&hv)[i] = hb_;
                ((u16*)&lv)[i] = f2bf(vp[i] - bf2f(hb_));
            }
            *(ushort4*)&Ah[srow * LSTR + sc4] = hv;
            *(ushort4*)&Al[srow * LSTR + sc4] = lv;
        }
        *(ushort4*)&Ah[srow * LSTR + 64 + sc4] = *(const ushort4*)&a1h[rb];
        *(ushort4*)&Al[srow * LSTR + 64 + sc4] = *(const ushort4*)&a1l[rb];
        *(ushort4*)&Ah[srow * LSTR + 128 + sc4] = *(const ushort4*)&tyh[rb];
        *(ushort4*)&Al[srow * LSTR + 128 + sc4] = *(const ushort4*)&tyl[rb];
        __syncthreads();

        f32x4 acc = {bv, bv, bv, bv};
#pragma unroll
        for (int c = 0; c < 6; ++c) {
            bf16x8 ah = *(const bf16x8*)&Ah[lrow * LSTR + c * 32 + lk8];
            bf16x8 al = *(const bf16x8*)&Al[lrow * LSTR + c * 32 + lk8];
            acc = __builtin_amdgcn_mfma_f32_16x16x32_bf16(ah, wh[c], acc, 0, 0, 0);
            acc = __builtin_amdgcn_mfma_f32_16x16x32_bf16(al, wh[c], acc, 0, 0, 0);
            acc = __builtin_amdgcn_mfma_f32_16x16x32_bf16(ah, wl[c], acc, 0, 0, 0);
        }
        __syncthreads();

#pragma unroll
        for (int j = 0; j < 4; ++j) {
            int row = r0 + (lane >> 4) * 4 + j;
            float v = fmaxf(acc[j], 0.0f);
            u16 hb_ = f2bf(v);
            ohi[((size_t)row << 6) + col] = hb_;
            olo[((size_t)row << 6) + col] = f2bf(v - bf2f(hb_));
        }
    }
}

__global__ __launch_bounds__(256) void dense2_mf(const u16* __restrict__ a0h,
                                                 const u16* __restrict__ a0l,
                                                 const u16* __restrict__ a1h,
                                                 const u16* __restrict__ a1l,
                                                 const u16* __restrict__ tyh,
                                                 const u16* __restrict__ tyl,
                                                 const float* __restrict__ W,
                                                 const float* __restrict__ bias,
                                                 float* __restrict__ out) {
    __shared__ u16 Ah[16 * LSTR], Al[16 * LSTR];
    __shared__ float Ls[16][48];
    const int tid = threadIdx.x, wid = tid >> 6, lane = tid & 63;
    const int lrow = lane & 15, lk8 = (lane >> 4) * 8;
    const int col = wid * 16 + lrow;
    const bool act = (wid < 3);
    const bool cok = act && (col < NCLS);

    bf16x8 wh[6], wl[6];
#pragma unroll
    for (int c = 0; c < 6; ++c) {
        bf16x8 h = 0, l = 0;
        if (cok) {
#pragma unroll
            for (int i = 0; i < 8; ++i) {
                float wv = foldW(W, c * 32 + lk8 + i, col, NCLS);
                u16 hb_ = f2bf(wv);
                h[i] = (short)hb_;
                l[i] = (short)f2bf(wv - bf2f(hb_));
            }
        }
        wh[c] = h; wl[c] = l;
    }
    float bv = cok ? bias[col] : 0.0f;
    const int srow = tid >> 4, sc4 = (tid & 15) * 4;

    for (int t = 0; t < DNT; ++t) {
        int r0 = (blockIdx.x * DNT + t) * 16;
        size_t rb = ((size_t)(r0 + srow) << 6) + sc4;
        *(ushort4*)&Ah[srow * LSTR + sc4] = *(const ushort4*)&a0h[rb];
        *(ushort4*)&Al[srow * LSTR + sc4] = *(const ushort4*)&a0l[rb];
        *(ushort4*)&Ah[srow * LSTR + 64 + sc4] = *(const ushort4*)&a1h[rb];
        *(ushort4*)&Al[srow * LSTR + 64 + sc4] = *(const ushort4*)&a1l[rb];
        *(ushort4*)&Ah[srow * LSTR + 128 + sc4] = *(const ushort4*)&tyh[rb];
        *(ushort4*)&Al[srow * LSTR + 128 + sc4] = *(const ushort4*)&tyl[rb];
        __syncthreads();

        if (act) {
            f32x4 acc = {bv, bv, bv, bv};
#pragma unroll
            for (int c = 0; c < 6; ++c) {
                bf16x8 ah = *(const bf16x8*)&Ah[lrow * LSTR + c * 32 + lk8];
                bf16x8 al = *(const bf16x8*)&Al[lrow * LSTR + c * 32 + lk8];
                acc = __builtin_amdgcn_mfma_f32_16x16x32_bf16(ah, wh[c], acc, 0, 0, 0);
                acc = __builtin_amdgcn_mfma_f32_16x16x32_bf16(al, wh[c], acc, 0, 0, 0);
                acc = __builtin_amdgcn_mfma_f32_16x16x32_bf16(ah, wl[c], acc, 0, 0, 0);
            }
#pragma unroll
            for (int j = 0; j < 4; ++j) Ls[(lane >> 4) * 4 + j][col] = acc[j];
        }
        __syncthreads();

        {   // softmax: 16 rows, one 16-lane group per row (4 rows per wave)
            int row = wid * 4 + (lane >> 4);
            int cg = lane & 15;
            float v0 = Ls[row][cg];
            float v1 = Ls[row][cg + 16];
            float v2 = (cg < 8) ? Ls[row][cg + 32] : -1e30f;
            float m = fmaxf(fmaxf(v0, v1), v2);
#pragma unroll
            for (int o = 8; o; o >>= 1) m = fmaxf(m, __shfl_xor(m, o));
            float e0 = expf(v0 - m), e1 = expf(v1 - m);
            float e2 = (cg < 8) ? expf(v2 - m) : 0.0f;
            float s = e0 + e1 + e2;
#pragma unroll
            for (int o = 8; o; o >>= 1) s += __shfl_xor(s, o);
            float inv = 1.0f / s;
            size_t ob = (size_t)(r0 + row) * NCLS;
            out[ob + cg] = e0 * inv;
            out[ob + cg + 16] = e1 * inv;
            if (cg < 8) out[ob + cg + 32] = e2 * inv;
        }
    }
}

// ---------------- host ----------------

extern "C" void kernel_launch(void* const* d_in, const int* in_sizes, int n_in,
                              void* d_out, int out_size, void* d_ws, size_t ws_size,
                              hipStream_t stream) {
    const float* x = (const float*)d_in[0];
    const int* edge_index = (const int*)d_in[1];
    const float* W1 = (const float*)d_in[2];
    const float* b1 = (const float*)d_in[3];
    const float* W2 = (const float*)d_in[4];
    const float* b2 = (const float*)d_in[5];
    float* out = (float*)d_out;

    const int* src = edge_index;
    const int* dst = edge_index + N_EDGES;

    char* ws = (char*)d_ws;
    size_t off = 0;
    auto carve = [&](size_t bytes) -> void* {
        void* p = ws + off;
        off = align256(off + bytes);
        return p;
    };
    int* gFillD = (int*)carve((size_t)NBUCK * 4);
    int* gFillS = (int*)carve((size_t)NBUCK * 4);
    size_t zero_bytes = off;
    u32* partD = (u32*)carve((size_t)NBUCK * CAPE * 4);     // 7.0 MB ((s<<9)|dlocal)
    u16* partS = (u16*)carve((size_t)NBUCK * CAPE * 2);     // 3.5 MB (bucket-local src)
    u32* csr = (u32*)carve((size_t)NBUCK * CAPC * 4 + 1024);// 8.4 MB (src|w15<<17)
    int2* meta = (int2*)carve((size_t)N_NODES * 8);         // 0.8 MB
    float* dis = (float*)carve((size_t)(N_NODES + 1) * 4);  // 0.4 MB
    const size_t FB = (size_t)(N_NODES + 1) * 64 * 2;       // 12.8 MB per bf16 plane (+DUMMY row)
    u16* xb  = (u16*)carve(FB);
    u16* t1h = (u16*)carve(FB);   // Tx1 / Th1 hi
    u16* t1l = (u16*)carve(FB);   // Tx1 / Th1 lo
    u16* tyh = (u16*)carve(FB);   // L.Tx1 / L.Th1 hi
    u16* tyl = (u16*)carve(FB);   // L.Tx1 / L.Th1 lo
    u16* hh  = (u16*)carve(FB);   // h hi (gather input for layer 2)
    u16* hl  = (u16*)carve(FB);   // h lo
    // total ~110 MB
    // NOTE: no DUMMY-row / dis[DUMMY] zeroing needed — pad entries carry packed
    // weight bits = 0 (fmaf(0, finite_poison, acc) is exact) and dis[DUMMY] is
    // never read (weights come pre-packed from build_csr).

    const int WV = (N_NODES * 64) / 256;    // 25000 (one wave per node)

    hipMemsetAsync(d_ws, 0, zero_bytes, stream);   // gFillD/gFillS only (1.6 KB)

    pscatter_conv<<<PS_BLOCKS + CONV_BLOCKS, 256, 0, stream>>>(src, dst, gFillD, gFillS,
                                                               partD, partS, x, xb);
    build_dis<<<NBUCK, 256, 0, stream>>>(partS, gFillS, dis);
    build_csr<<<NBUCK, 256, 0, stream>>>(partD, gFillD, dis, csr, meta);

    // layer 1: Tx1 = L.x ; Ty = L.Tx1 ; h = relu(x@(W0-W2) + Tx1@W1 + Ty@2W2 + b1)
    spmm<<<WV, 256, 0, stream>>>(xb, dis, meta, csr, t1h, t1l);
    spmm<<<WV, 256, 0, stream>>>(t1h, dis, meta, csr, tyh, tyl);
    dense1_mf<<<DGRID, 256, 0, stream>>>(x, t1h, t1l, tyh, tyl, W1, b1, hh, hl);

    // layer 2 (t1/ty planes reused)
    spmm<<<WV, 256, 0, stream>>>(hh, dis, meta, csr, t1h, t1l);
    spmm<<<WV, 256, 0, stream>>>(t1h, dis, meta, csr, tyh, tyl);
    dense2_mf<<<DGRID, 256, 0, stream>>>(hh, hl, t1h, t1l, tyh, tyl, W2, b2, out);
}

// Round 15
// 236.519 us; speedup vs baseline: 1.1700x; 1.0553x over previous
//
#include <hip/hip_runtime.h>
#include <hip/hip_fp16.h>

#define N_NODES 100000
#define N_EDGES 1600000
#define NCLS 40
#define NBUCK 196          // buckets of 512 nodes; bucket = id >> 9
#define CAPE 8960          // per-bucket edge capacity
#define CAPC 10752         // per-bucket CSR capacity incl. x8 padding
#define DUMMY N_NODES      // pad source id; packed w bits = 0 -> exact no-op

typedef unsigned short u16;
typedef unsigned int u32;
typedef short bf16x8 __attribute__((ext_vector_type(8)));
typedef float f32x4 __attribute__((ext_vector_type(4)));

static inline size_t align256(size_t x) { return (x + 255) & ~(size_t)255; }

__device__ __forceinline__ float bf2f(u16 h) { return __uint_as_float(((u32)h) << 16); }
__device__ __forceinline__ u16 f2bf(float f) {
    u32 u = __float_as_uint(f);
    u += 0x7FFFu + ((u >> 16) & 1u);  // round-to-nearest-even
    return (u16)(u >> 16);
}
__device__ __forceinline__ u32 pk2(u16 a, u16 b) { return (u32)a | ((u32)b << 16); }
__device__ __forceinline__ u32 pack15(float f) {   // positive fp16 sans sign bit
    return ((u32)__half_as_ushort(__float2half(f))) & 0x7FFFu;
}
__device__ __forceinline__ float unpack15(u32 bits) {
    return __half2float(__ushort_as_half((u16)bits));
}
__device__ __forceinline__ float blo(u32 v) { return __uint_as_float(v << 16); }
__device__ __forceinline__ float bhi(u32 v) { return __uint_as_float(v & 0xFFFF0000u); }

// ---------- pass 1: LDS-histogram partition by bucket + fused x->bf16 ----------
#define PS_BLOCKS 391
#define CONV_BLOCKS 6250

__global__ __launch_bounds__(256) void pscatter_conv(const int* __restrict__ src,
                                                     const int* __restrict__ dst,
                                                     int* __restrict__ gFillD,
                                                     int* __restrict__ gFillS,
                                                     u32* __restrict__ partD,
                                                     u16* __restrict__ partS,
                                                     const float* __restrict__ x,
                                                     u16* __restrict__ xb) {
    if (blockIdx.x >= PS_BLOCKS) {
        int i = (blockIdx.x - PS_BLOCKS) * 256 + threadIdx.x;  // 4 floats/thread
        float4 v = *(const float4*)(x + (size_t)i * 4);
        ushort4 o;
        o.x = f2bf(v.x); o.y = f2bf(v.y); o.z = f2bf(v.z); o.w = f2bf(v.w);
        *(ushort4*)(xb + (size_t)i * 4) = o;
        return;
    }
    __shared__ int histD[NBUCK], histS[NBUCK], chunkD[NBUCK], chunkS[NBUCK];
    int tid = threadIdx.x;
    int base = blockIdx.x * 4096;

    int4 sv[4], dv[4];
#pragma unroll
    for (int j = 0; j < 4; ++j) {
        int idx = base + j * 1024 + tid * 4;
        if (idx < N_EDGES) {
            sv[j] = *(const int4*)(src + idx);
            dv[j] = *(const int4*)(dst + idx);
        } else {
            sv[j] = make_int4(0, 0, 0, 0);
            dv[j] = make_int4(0, 0, 0, 0);
        }
    }

    for (int i = tid; i < NBUCK; i += 256) { histD[i] = 0; histS[i] = 0; }
    __syncthreads();
#pragma unroll
    for (int j = 0; j < 4; ++j)
#pragma unroll
        for (int k = 0; k < 4; ++k) {
            int s = ((const int*)&sv[j])[k], d = ((const int*)&dv[j])[k];
            if (s != d) {
                atomicAdd(&histD[d >> 9], 1);
                atomicAdd(&histS[s >> 9], 1);
            }
        }
    __syncthreads();
    for (int B = tid; B < NBUCK; B += 256) {
        int cD = histD[B];
        chunkD[B] = cD ? atomicAdd(&gFillD[B], cD) : 0;
        int cS = histS[B];
        chunkS[B] = cS ? atomicAdd(&gFillS[B], cS) : 0;
    }
    __syncthreads();
    for (int i = tid; i < NBUCK; i += 256) { histD[i] = 0; histS[i] = 0; }
    __syncthreads();
#pragma unroll
    for (int j = 0; j < 4; ++j)
#pragma unroll
        for (int k = 0; k < 4; ++k) {
            int s = ((const int*)&sv[j])[k], d = ((const int*)&dv[j])[k];
            if (s != d) {
                int bD = d >> 9;
                int r = atomicAdd(&histD[bD], 1);
                int o = chunkD[bD] + r;
                if (o < CAPE) partD[bD * CAPE + o] = ((u32)s << 9) | (u32)(d & 511);
                int bS = s >> 9;
                int r2 = atomicAdd(&histS[bS], 1);
                int o2 = chunkS[bS] + r2;
                if (o2 < CAPE) partS[bS * CAPE + o2] = (u16)(s & 511);
            }
        }
}

// ---------- pass 2a: src-side out-degree histogram -> dis ----------
__global__ __launch_bounds__(256) void build_dis(const u16* __restrict__ partS,
                                                 const int* __restrict__ gFillS,
                                                 float* __restrict__ dis) {
    __shared__ int cnt[512];
    int tid = threadIdx.x;
    int B = blockIdx.x;
    for (int i = tid; i < 512; i += 256) cnt[i] = 0;
    __syncthreads();
    int nS = min(gFillS[B], CAPE);
    for (int i = tid; i < nS; i += 256) atomicAdd(&cnt[partS[B * CAPE + i]], 1);
    __syncthreads();
    for (int n = tid; n < 512; n += 256) {
        int node = B * 512 + n;
        if (node < N_NODES) {
            int dg = cnt[n];
            dis[node] = dg > 0 ? 1.0f / sqrtf((float)dg) : 0.0f;
        }
    }
}

// ---------- pass 2b: CSR build (plain rank order); entry = src | fp15(dis[src])<<17 ----------
__global__ __launch_bounds__(256) void build_csr(const u32* __restrict__ partD,
                                                 const int* __restrict__ gFillD,
                                                 const float* __restrict__ dis,
                                                 u32* __restrict__ csr,
                                                 int2* __restrict__ meta) {
    __shared__ int cnt[512], loc[512], rnk[512];
    int tid = threadIdx.x;
    int B = blockIdx.x;
    for (int i = tid; i < 512; i += 256) { cnt[i] = 0; rnk[i] = 0; }
    __syncthreads();
    int nD = min(gFillD[B], CAPE);
    for (int i = tid; i < nD; i += 256) atomicAdd(&cnt[partD[B * CAPE + i] & 511], 1);
    __syncthreads();
    if (tid < 64) {
        int bb = tid * 8, c8[8], mysum = 0;
#pragma unroll
        for (int j = 0; j < 8; ++j) { c8[j] = (cnt[bb + j] + 7) & ~7; mysum += c8[j]; }
        int incl = mysum;
#pragma unroll
        for (int off = 1; off < 64; off <<= 1) {
            int v = __shfl_up(incl, off);
            if (tid >= off) incl += v;
        }
        int run = incl - mysum;
#pragma unroll
        for (int j = 0; j < 8; ++j) { loc[bb + j] = run; run += c8[j]; }
    }
    __syncthreads();
    for (int n = tid; n < 512; n += 256) {
        int node = B * 512 + n;
        if (node < N_NODES) {
            int c = cnt[n], c8 = (c + 7) & ~7;
            meta[node] = make_int2(B * CAPC + loc[n], c);
            for (int e = c; e < c8; ++e) csr[B * CAPC + loc[n] + e] = (u32)DUMMY;
        }
    }
    for (int i = tid; i < nD; i += 256) {
        u32 p = partD[B * CAPE + i];
        int ln = p & 511;
        u32 s = p >> 9;
        int r = atomicAdd(&rnk[ln], 1);
        int pos = loc[ln] + r;
        if (pos < CAPC) csr[B * CAPC + pos] = s | (pack15(dis[s]) << 17);
    }
}

// ---------- SPMM gather: 8 nodes/wave, 8 lanes/node, lane = 8 features (dwordx4 row) ----------
// Per 8-edge step across the wave (64 edges): 1 csr dword gather + 8 row loads.
// Entry broadcast within each 8-lane group via ds_swizzle with constant offset
// (J<<5)|0x18 : new_lane = (lane & 0x18) | J  — template J makes it a literal.
template <int J>
__device__ __forceinline__ void edge_step(u32 ent, const uint4* __restrict__ in4,
                                          int p, float* a) {
    u32 q = (u32)__builtin_amdgcn_ds_swizzle((int)ent, (J << 5) | 0x18);
    u32 s = q & 0x1FFFFu;
    float w = unpack15(q >> 17);           // pad entries: w bits = 0 -> exact no-op
    uint4 v = in4[((size_t)s << 3) + p];
    a[0] = fmaf(w, blo(v.x), a[0]);
    a[1] = fmaf(w, bhi(v.x), a[1]);
    a[2] = fmaf(w, blo(v.y), a[2]);
    a[3] = fmaf(w, bhi(v.y), a[3]);
    a[4] = fmaf(w, blo(v.z), a[4]);
    a[5] = fmaf(w, bhi(v.z), a[5]);
    a[6] = fmaf(w, blo(v.w), a[6]);
    a[7] = fmaf(w, bhi(v.w), a[7]);
}

#define SPMM_BLOCKS 3125   // 3125 blocks * 4 waves * 8 nodes = 100000 exactly

__global__ __launch_bounds__(256) void spmm(const u16* __restrict__ in,     // (N+1)x64 bf16
                                            const float* __restrict__ dis,
                                            const int2* __restrict__ meta,
                                            const u32* __restrict__ csr,
                                            u16* __restrict__ outhi,
                                            u16* __restrict__ outlo) {
    const int tid = threadIdx.x;
    const int lane = tid & 63;
    const int gw = blockIdx.x * 4 + (tid >> 6);   // global wave id
    const int node = gw * 8 + (lane >> 3);        // 8 nodes per wave (exact fit)
    const int p = lane & 7;                        // feature chunk [8p, 8p+8)

    int2 mt = meta[node];
    int c8 = (mt.y + 7) & ~7;                      // list DUMMY-padded to x8
    const u32* lst = csr + mt.x;
    const uint4* in4 = (const uint4*)in;

    float a[8] = {0.f, 0.f, 0.f, 0.f, 0.f, 0.f, 0.f, 0.f};

    for (int e = 0; e < c8; e += 8) {
        u32 ent = lst[e + p];                      // lane p holds group's entry e+p
        edge_step<0>(ent, in4, p, a);
        edge_step<1>(ent, in4, p, a);
        edge_step<2>(ent, in4, p, a);
        edge_step<3>(ent, in4, p, a);
        edge_step<4>(ent, in4, p, a);
        edge_step<5>(ent, in4, p, a);
        edge_step<6>(ent, in4, p, a);
        edge_step<7>(ent, in4, p, a);
    }

    float vd = -dis[node];
    float f0 = vd * a[0], f1 = vd * a[1], f2 = vd * a[2], f3 = vd * a[3];
    float f4 = vd * a[4], f5 = vd * a[5], f6 = vd * a[6], f7 = vd * a[7];

    u16 h0 = f2bf(f0), h1 = f2bf(f1), h2 = f2bf(f2), h3 = f2bf(f3);
    u16 h4 = f2bf(f4), h5 = f2bf(f5), h6 = f2bf(f6), h7 = f2bf(f7);
    uint4 H;
    H.x = pk2(h0, h1); H.y = pk2(h2, h3); H.z = pk2(h4, h5); H.w = pk2(h6, h7);
    *((uint4*)((u32*)outhi + (((size_t)node << 5) + (p << 2)))) = H;

    uint4 L;
    L.x = pk2(f2bf(f0 - bf2f(h0)), f2bf(f1 - bf2f(h1)));
    L.y = pk2(f2bf(f2 - bf2f(h2)), f2bf(f3 - bf2f(h3)));
    L.z = pk2(f2bf(f4 - bf2f(h4)), f2bf(f5 - bf2f(h5)));
    L.w = pk2(f2bf(f6 - bf2f(h6)), f2bf(f7 - bf2f(h7)));
    *((uint4*)((u32*)outlo + (((size_t)node << 5) + (p << 2)))) = L;
}

// ---------- dense via MFMA, split-bf16, Chebyshev fold in the weights ----------
// out = A0@(W0 - W2) + A1@W1 + Ty@(2*W2)   where Ty = L.A1
#define DGRID 1250
#define DNT 5              // 1250 * 5 * 16 = 100000 rows exactly (round-10 proven)
#define LSTR 200           // u16 per LDS row (192 data + 8 pad)

__device__ __forceinline__ float foldW(const float* __restrict__ W, int kk, int col,
                                       int ncols) {
    float wv = W[kk * ncols + col];
    if (kk < 64) wv -= W[(kk + 128) * ncols + col];   // W0 - W2
    else if (kk >= 128) wv += wv;                     // 2 * W2
    return wv;
}

__global__ __launch_bounds__(256) void dense1_mf(const float* __restrict__ x,
                                                 const u16* __restrict__ a1h,
                                                 const u16* __restrict__ a1l,
                                                 const u16* __restrict__ tyh,
                                                 const u16* __restrict__ tyl,
                                                 const float* __restrict__ W,
                                                 const float* __restrict__ bias,
                                                 u16* __restrict__ ohi,
                                                 u16* __restrict__ olo) {
    __shared__ u16 Ah[16 * LSTR], Al[16 * LSTR];
    const int tid = threadIdx.x, wid = tid >> 6, lane = tid & 63;
    const int lrow = lane & 15, lk8 = (lane >> 4) * 8;
    const int col = wid * 16 + lrow;

    bf16x8 wh[6], wl[6];
#pragma unroll
    for (int c = 0; c < 6; ++c) {
        bf16x8 h, l;
#pragma unroll
        for (int i = 0; i < 8; ++i) {
            float wv = foldW(W, c * 32 + lk8 + i, col, 64);
            u16 hb_ = f2bf(wv);
            h[i] = (short)hb_;
            l[i] = (short)f2bf(wv - bf2f(hb_));
        }
        wh[c] = h; wl[c] = l;
    }
    float bv = bias[col];
    const int srow = tid >> 4, sc4 = (tid & 15) * 4;

    for (int t = 0; t < DNT; ++t) {
        int r0 = (blockIdx.x * DNT + t) * 16;
        size_t rb = ((size_t)(r0 + srow) << 6) + sc4;
        {
            float4 v = *(const float4*)&x[rb];
            const float* vp = (const float*)&v;
            ushort4 hv, lv;
#pragma unroll
            for (int i = 0; i < 4; ++i) {
                u16 hb_ = f2bf(vp[i]);
                ((u16*)&hv)[i] = hb_;
                ((u16*)&lv)[i] = f2bf(vp[i] - bf2f(hb_));
            }
            *(ushort4*)&Ah[srow * LSTR + sc4] = hv;
            *(ushort4*)&Al[srow * LSTR + sc4] = lv;
        }
        *(ushort4*)&Ah[srow * LSTR + 64 + sc4] = *(const ushort4*)&a1h[rb];
        *(ushort4*)&Al[srow * LSTR + 64 + sc4] = *(const ushort4*)&a1l[rb];
        *(ushort4*)&Ah[srow * LSTR + 128 + sc4] = *(const ushort4*)&tyh[rb];
        *(ushort4*)&Al[srow * LSTR + 128 + sc4] = *(const ushort4*)&tyl[rb];
        __syncthreads();

        f32x4 acc = {bv, bv, bv, bv};
#pragma unroll
        for (int c = 0; c < 6; ++c) {
            bf16x8 ah = *(const bf16x8*)&Ah[lrow * LSTR + c * 32 + lk8];
            bf16x8 al = *(const bf16x8*)&Al[lrow * LSTR + c * 32 + lk8];
            acc = __builtin_amdgcn_mfma_f32_16x16x32_bf16(ah, wh[c], acc, 0, 0, 0);
            acc = __builtin_amdgcn_mfma_f32_16x16x32_bf16(al, wh[c], acc, 0, 0, 0);
            acc = __builtin_amdgcn_mfma_f32_16x16x32_bf16(ah, wl[c], acc, 0, 0, 0);
        }
        __syncthreads();

#pragma unroll
        for (int j = 0; j < 4; ++j) {
            int row = r0 + (lane >> 4) * 4 + j;
            float v = fmaxf(acc[j], 0.0f);
            u16 hb_ = f2bf(v);
            ohi[((size_t)row << 6) + col] = hb_;
            olo[((size_t)row << 6) + col] = f2bf(v - bf2f(hb_));
        }
    }
}

__global__ __launch_bounds__(256) void dense2_mf(const u16* __restrict__ a0h,
                                                 const u16* __restrict__ a0l,
                                                 const u16* __restrict__ a1h,
                                                 const u16* __restrict__ a1l,
                                                 const u16* __restrict__ tyh,
                                                 const u16* __restrict__ tyl,
                                                 const float* __restrict__ W,
                                                 const float* __restrict__ bias,
                                                 float* __restrict__ out) {
    __shared__ u16 Ah[16 * LSTR], Al[16 * LSTR];
    __shared__ float Ls[16][48];
    const int tid = threadIdx.x, wid = tid >> 6, lane = tid & 63;
    const int lrow = lane & 15, lk8 = (lane >> 4) * 8;
    const int col = wid * 16 + lrow;
    const bool act = (wid < 3);
    const bool cok = act && (col < NCLS);

    bf16x8 wh[6], wl[6];
#pragma unroll
    for (int c = 0; c < 6; ++c) {
        bf16x8 h = 0, l = 0;
        if (cok) {
#pragma unroll
            for (int i = 0; i < 8; ++i) {
                float wv = foldW(W, c * 32 + lk8 + i, col, NCLS);
                u16 hb_ = f2bf(wv);
                h[i] = (short)hb_;
                l[i] = (short)f2bf(wv - bf2f(hb_));
            }
        }
        wh[c] = h; wl[c] = l;
    }
    float bv = cok ? bias[col] : 0.0f;
    const int srow = tid >> 4, sc4 = (tid & 15) * 4;

    for (int t = 0; t < DNT; ++t) {
        int r0 = (blockIdx.x * DNT + t) * 16;
        size_t rb = ((size_t)(r0 + srow) << 6) + sc4;
        *(ushort4*)&Ah[srow * LSTR + sc4] = *(const ushort4*)&a0h[rb];
        *(ushort4*)&Al[srow * LSTR + sc4] = *(const ushort4*)&a0l[rb];
        *(ushort4*)&Ah[srow * LSTR + 64 + sc4] = *(const ushort4*)&a1h[rb];
        *(ushort4*)&Al[srow * LSTR + 64 + sc4] = *(const ushort4*)&a1l[rb];
        *(ushort4*)&Ah[srow * LSTR + 128 + sc4] = *(const ushort4*)&tyh[rb];
        *(ushort4*)&Al[srow * LSTR + 128 + sc4] = *(const ushort4*)&tyl[rb];
        __syncthreads();

        if (act) {
            f32x4 acc = {bv, bv, bv, bv};
#pragma unroll
            for (int c = 0; c < 6; ++c) {
                bf16x8 ah = *(const bf16x8*)&Ah[lrow * LSTR + c * 32 + lk8];
                bf16x8 al = *(const bf16x8*)&Al[lrow * LSTR + c * 32 + lk8];
                acc = __builtin_amdgcn_mfma_f32_16x16x32_bf16(ah, wh[c], acc, 0, 0, 0);
                acc = __builtin_amdgcn_mfma_f32_16x16x32_bf16(al, wh[c], acc, 0, 0, 0);
                acc = __builtin_amdgcn_mfma_f32_16x16x32_bf16(ah, wl[c], acc, 0, 0, 0);
            }
#pragma unroll
            for (int j = 0; j < 4; ++j) Ls[(lane >> 4) * 4 + j][col] = acc[j];
        }
        __syncthreads();

        {   // softmax: 16 rows, one 16-lane group per row (4 rows per wave)
            int row = wid * 4 + (lane >> 4);
            int cg = lane & 15;
            float v0 = Ls[row][cg];
            float v1 = Ls[row][cg + 16];
            float v2 = (cg < 8) ? Ls[row][cg + 32] : -1e30f;
            float m = fmaxf(fmaxf(v0, v1), v2);
#pragma unroll
            for (int o = 8; o; o >>= 1) m = fmaxf(m, __shfl_xor(m, o));
            float e0 = expf(v0 - m), e1 = expf(v1 - m);
            float e2 = (cg < 8) ? expf(v2 - m) : 0.0f;
            float s = e0 + e1 + e2;
#pragma unroll
            for (int o = 8; o; o >>= 1) s += __shfl_xor(s, o);
            float inv = 1.0f / s;
            size_t ob = (size_t)(r0 + row) * NCLS;
            out[ob + cg] = e0 * inv;
            out[ob + cg + 16] = e1 * inv;
            if (cg < 8) out[ob + cg + 32] = e2 * inv;
        }
    }
}

// ---------------- host ----------------

extern "C" void kernel_launch(void* const* d_in, const int* in_sizes, int n_in,
                              void* d_out, int out_size, void* d_ws, size_t ws_size,
                              hipStream_t stream) {
    const float* x = (const float*)d_in[0];
    const int* edge_index = (const int*)d_in[1];
    const float* W1 = (const float*)d_in[2];
    const float* b1 = (const float*)d_in[3];
    const float* W2 = (const float*)d_in[4];
    const float* b2 = (const float*)d_in[5];
    float* out = (float*)d_out;

    const int* src = edge_index;
    const int* dst = edge_index + N_EDGES;

    char* ws = (char*)d_ws;
    size_t off = 0;
    auto carve = [&](size_t bytes) -> void* {
        void* p = ws + off;
        off = align256(off + bytes);
        return p;
    };
    int* gFillD = (int*)carve((size_t)NBUCK * 4);
    int* gFillS = (int*)carve((size_t)NBUCK * 4);
    size_t zero_bytes = off;
    u32* partD = (u32*)carve((size_t)NBUCK * CAPE * 4);     // 7.0 MB ((s<<9)|dlocal)
    u16* partS = (u16*)carve((size_t)NBUCK * CAPE * 2);     // 3.5 MB (bucket-local src)
    u32* csr = (u32*)carve((size_t)NBUCK * CAPC * 4 + 1024);// 8.4 MB (src|w15<<17)
    int2* meta = (int2*)carve((size_t)N_NODES * 8);         // 0.8 MB
    float* dis = (float*)carve((size_t)(N_NODES + 1) * 4);  // 0.4 MB
    const size_t FB = (size_t)(N_NODES + 1) * 64 * 2;       // 12.8 MB per bf16 plane (+DUMMY row)
    u16* xb  = (u16*)carve(FB);
    u16* t1h = (u16*)carve(FB);   // Tx1 / Th1 hi
    u16* t1l = (u16*)carve(FB);   // Tx1 / Th1 lo
    u16* tyh = (u16*)carve(FB);   // L.Tx1 / L.Th1 hi
    u16* tyl = (u16*)carve(FB);   // L.Tx1 / L.Th1 lo
    u16* hh  = (u16*)carve(FB);   // h hi (gather input for layer 2)
    u16* hl  = (u16*)carve(FB);   // h lo
    // total ~110 MB
    // NOTE: no DUMMY-row / dis zeroing needed — pad entries carry packed weight
    // bits = 0 (fmaf(0, finite_poison, acc) is exact; 0xAA poison is finite bf16).

    (void)hipMemsetAsync(d_ws, 0, zero_bytes, stream);   // gFillD/gFillS only (1.6 KB)

    pscatter_conv<<<PS_BLOCKS + CONV_BLOCKS, 256, 0, stream>>>(src, dst, gFillD, gFillS,
                                                               partD, partS, x, xb);
    build_dis<<<NBUCK, 256, 0, stream>>>(partS, gFillS, dis);
    build_csr<<<NBUCK, 256, 0, stream>>>(partD, gFillD, dis, csr, meta);

    // layer 1: Tx1 = L.x ; Ty = L.Tx1 ; h = relu(x@(W0-W2) + Tx1@W1 + Ty@2W2 + b1)
    spmm<<<SPMM_BLOCKS, 256, 0, stream>>>(xb, dis, meta, csr, t1h, t1l);
    spmm<<<SPMM_BLOCKS, 256, 0, stream>>>(t1h, dis, meta, csr, tyh, tyl);
    dense1_mf<<<DGRID, 256, 0, stream>>>(x, t1h, t1l, tyh, tyl, W1, b1, hh, hl);

    // layer 2 (t1/ty planes reused)
    spmm<<<SPMM_BLOCKS, 256, 0, stream>>>(hh, dis, meta, csr, t1h, t1l);
    spmm<<<SPMM_BLOCKS, 256, 0, stream>>>(t1h, dis, meta, csr, tyh, tyl);
    dense2_mf<<<DGRID, 256, 0, stream>>>(hh, hl, t1h, t1l, tyh, tyl, W2, b2, out);
}

// Round 16
// 222.569 us; speedup vs baseline: 1.2433x; 1.0627x over previous
//
#include <hip/hip_runtime.h>
#include <hip/hip_fp16.h>

#define N_NODES 100000
#define N_EDGES 1600000
#define NCLS 40
#define NBUCK 196          // buckets of 512 nodes; bucket = id >> 9
#define CAPE 8960          // per-bucket edge capacity
#define CAPC 10752         // per-bucket CSR capacity incl. x8 padding
#define DUMMY N_NODES      // pad source id; packed w bits = 0 -> exact no-op

typedef unsigned short u16;
typedef unsigned int u32;
typedef short bf16x8 __attribute__((ext_vector_type(8)));
typedef float f32x4 __attribute__((ext_vector_type(4)));

static inline size_t align256(size_t x) { return (x + 255) & ~(size_t)255; }

__device__ __forceinline__ float bf2f(u16 h) { return __uint_as_float(((u32)h) << 16); }
__device__ __forceinline__ u16 f2bf(float f) {
    u32 u = __float_as_uint(f);
    u += 0x7FFFu + ((u >> 16) & 1u);  // round-to-nearest-even
    return (u16)(u >> 16);
}
__device__ __forceinline__ u32 pk2(u16 a, u16 b) { return (u32)a | ((u32)b << 16); }
__device__ __forceinline__ u32 pack15(float f) {   // positive fp16 sans sign bit
    return ((u32)__half_as_ushort(__float2half(f))) & 0x7FFFu;
}
__device__ __forceinline__ float unpack15(u32 bits) {
    return __half2float(__ushort_as_half((u16)bits));
}
__device__ __forceinline__ float blo(u32 v) { return __uint_as_float(v << 16); }
__device__ __forceinline__ float bhi(u32 v) { return __uint_as_float(v & 0xFFFF0000u); }

// ---------- pass 1: LDS-histogram partition by bucket + fused x->bf16 ----------
#define PS_BLOCKS 391
#define CONV_BLOCKS 6250

__global__ __launch_bounds__(256) void pscatter_conv(const int* __restrict__ src,
                                                     const int* __restrict__ dst,
                                                     int* __restrict__ gFillD,
                                                     int* __restrict__ gFillS,
                                                     u32* __restrict__ partD,
                                                     u16* __restrict__ partS,
                                                     const float* __restrict__ x,
                                                     u16* __restrict__ xb) {
    if (blockIdx.x >= PS_BLOCKS) {
        int i = (blockIdx.x - PS_BLOCKS) * 256 + threadIdx.x;  // 4 floats/thread
        float4 v = *(const float4*)(x + (size_t)i * 4);
        ushort4 o;
        o.x = f2bf(v.x); o.y = f2bf(v.y); o.z = f2bf(v.z); o.w = f2bf(v.w);
        *(ushort4*)(xb + (size_t)i * 4) = o;
        return;
    }
    __shared__ int histD[NBUCK], histS[NBUCK], chunkD[NBUCK], chunkS[NBUCK];
    int tid = threadIdx.x;
    int base = blockIdx.x * 4096;

    int4 sv[4], dv[4];
#pragma unroll
    for (int j = 0; j < 4; ++j) {
        int idx = base + j * 1024 + tid * 4;
        if (idx < N_EDGES) {
            sv[j] = *(const int4*)(src + idx);
            dv[j] = *(const int4*)(dst + idx);
        } else {
            sv[j] = make_int4(0, 0, 0, 0);
            dv[j] = make_int4(0, 0, 0, 0);
        }
    }

    for (int i = tid; i < NBUCK; i += 256) { histD[i] = 0; histS[i] = 0; }
    __syncthreads();
#pragma unroll
    for (int j = 0; j < 4; ++j)
#pragma unroll
        for (int k = 0; k < 4; ++k) {
            int s = ((const int*)&sv[j])[k], d = ((const int*)&dv[j])[k];
            if (s != d) {
                atomicAdd(&histD[d >> 9], 1);
                atomicAdd(&histS[s >> 9], 1);
            }
        }
    __syncthreads();
    for (int B = tid; B < NBUCK; B += 256) {
        int cD = histD[B];
        chunkD[B] = cD ? atomicAdd(&gFillD[B], cD) : 0;
        int cS = histS[B];
        chunkS[B] = cS ? atomicAdd(&gFillS[B], cS) : 0;
    }
    __syncthreads();
    for (int i = tid; i < NBUCK; i += 256) { histD[i] = 0; histS[i] = 0; }
    __syncthreads();
#pragma unroll
    for (int j = 0; j < 4; ++j)
#pragma unroll
        for (int k = 0; k < 4; ++k) {
            int s = ((const int*)&sv[j])[k], d = ((const int*)&dv[j])[k];
            if (s != d) {
                int bD = d >> 9;
                int r = atomicAdd(&histD[bD], 1);
                int o = chunkD[bD] + r;
                if (o < CAPE) partD[bD * CAPE + o] = ((u32)s << 9) | (u32)(d & 511);
                int bS = s >> 9;
                int r2 = atomicAdd(&histS[bS], 1);
                int o2 = chunkS[bS] + r2;
                if (o2 < CAPE) partS[bS * CAPE + o2] = (u16)(s & 511);
            }
        }
}

// ---------- pass 2a: src-side out-degree histogram -> dis ----------
__global__ __launch_bounds__(256) void build_dis(const u16* __restrict__ partS,
                                                 const int* __restrict__ gFillS,
                                                 float* __restrict__ dis) {
    __shared__ int cnt[512];
    int tid = threadIdx.x;
    int B = blockIdx.x;
    for (int i = tid; i < 512; i += 256) cnt[i] = 0;
    __syncthreads();
    int nS = min(gFillS[B], CAPE);
    for (int i = tid; i < nS; i += 256) atomicAdd(&cnt[partS[B * CAPE + i]], 1);
    __syncthreads();
    for (int n = tid; n < 512; n += 256) {
        int node = B * 512 + n;
        if (node < N_NODES) {
            int dg = cnt[n];
            dis[node] = dg > 0 ? 1.0f / sqrtf((float)dg) : 0.0f;
        }
    }
}

// ---------- pass 2b: CSR build (plain rank order); entry = src | fp15(dis[src])<<17 ----------
__global__ __launch_bounds__(256) void build_csr(const u32* __restrict__ partD,
                                                 const int* __restrict__ gFillD,
                                                 const float* __restrict__ dis,
                                                 u32* __restrict__ csr,
                                                 int2* __restrict__ meta) {
    __shared__ int cnt[512], loc[512], rnk[512];
    int tid = threadIdx.x;
    int B = blockIdx.x;
    for (int i = tid; i < 512; i += 256) { cnt[i] = 0; rnk[i] = 0; }
    __syncthreads();
    int nD = min(gFillD[B], CAPE);
    for (int i = tid; i < nD; i += 256) atomicAdd(&cnt[partD[B * CAPE + i] & 511], 1);
    __syncthreads();
    if (tid < 64) {
        int bb = tid * 8, c8[8], mysum = 0;
#pragma unroll
        for (int j = 0; j < 8; ++j) { c8[j] = (cnt[bb + j] + 7) & ~7; mysum += c8[j]; }
        int incl = mysum;
#pragma unroll
        for (int off = 1; off < 64; off <<= 1) {
            int v = __shfl_up(incl, off);
            if (tid >= off) incl += v;
        }
        int run = incl - mysum;
#pragma unroll
        for (int j = 0; j < 8; ++j) { loc[bb + j] = run; run += c8[j]; }
    }
    __syncthreads();
    for (int n = tid; n < 512; n += 256) {
        int node = B * 512 + n;
        if (node < N_NODES) {
            int c = cnt[n], c8 = (c + 7) & ~7;
            meta[node] = make_int2(B * CAPC + loc[n], c);
            for (int e = c; e < c8; ++e) csr[B * CAPC + loc[n] + e] = (u32)DUMMY;
        }
    }
    for (int i = tid; i < nD; i += 256) {
        u32 p = partD[B * CAPE + i];
        int ln = p & 511;
        u32 s = p >> 9;
        int r = atomicAdd(&rnk[ln], 1);
        int pos = loc[ln] + r;
        if (pos < CAPC) csr[B * CAPC + pos] = s | (pack15(dis[s]) << 17);
    }
}

// ---------- SPMM gather: 8 nodes/wave, 8 lanes/node, lane = 8 features (dwordx4 row) ----------
// hi-plane-only output (lo planes of Tx1/Ty are numerically dead — see round-16 note).
template <int J>
__device__ __forceinline__ void edge_step(u32 ent, const uint4* __restrict__ in4,
                                          int p, float* a) {
    u32 q = (u32)__builtin_amdgcn_ds_swizzle((int)ent, (J << 5) | 0x18);
    u32 s = q & 0x1FFFFu;
    float w = unpack15(q >> 17);           // pad entries: w bits = 0 -> exact no-op
    uint4 v = in4[((size_t)s << 3) + p];
    a[0] = fmaf(w, blo(v.x), a[0]);
    a[1] = fmaf(w, bhi(v.x), a[1]);
    a[2] = fmaf(w, blo(v.y), a[2]);
    a[3] = fmaf(w, bhi(v.y), a[3]);
    a[4] = fmaf(w, blo(v.z), a[4]);
    a[5] = fmaf(w, bhi(v.z), a[5]);
    a[6] = fmaf(w, blo(v.w), a[6]);
    a[7] = fmaf(w, bhi(v.w), a[7]);
}

#define SPMM_BLOCKS 3125   // 3125 blocks * 4 waves * 8 nodes = 100000 exactly

__global__ __launch_bounds__(256) void spmm(const u16* __restrict__ in,     // (N+1)x64 bf16
                                            const float* __restrict__ dis,
                                            const int2* __restrict__ meta,
                                            const u32* __restrict__ csr,
                                            u16* __restrict__ outhi) {
    const int tid = threadIdx.x;
    const int lane = tid & 63;
    const int gw = blockIdx.x * 4 + (tid >> 6);   // global wave id
    const int node = gw * 8 + (lane >> 3);        // 8 nodes per wave (exact fit)
    const int p = lane & 7;                        // feature chunk [8p, 8p+8)

    int2 mt = meta[node];
    int c8 = (mt.y + 7) & ~7;                      // list DUMMY-padded to x8
    const u32* lst = csr + mt.x;
    const uint4* in4 = (const uint4*)in;

    float a[8] = {0.f, 0.f, 0.f, 0.f, 0.f, 0.f, 0.f, 0.f};

    for (int e = 0; e < c8; e += 8) {
        u32 ent = lst[e + p];                      // lane p holds group's entry e+p
        edge_step<0>(ent, in4, p, a);
        edge_step<1>(ent, in4, p, a);
        edge_step<2>(ent, in4, p, a);
        edge_step<3>(ent, in4, p, a);
        edge_step<4>(ent, in4, p, a);
        edge_step<5>(ent, in4, p, a);
        edge_step<6>(ent, in4, p, a);
        edge_step<7>(ent, in4, p, a);
    }

    float vd = -dis[node];
    uint4 H;
    H.x = pk2(f2bf(vd * a[0]), f2bf(vd * a[1]));
    H.y = pk2(f2bf(vd * a[2]), f2bf(vd * a[3]));
    H.z = pk2(f2bf(vd * a[4]), f2bf(vd * a[5]));
    H.w = pk2(f2bf(vd * a[6]), f2bf(vd * a[7]));
    *((uint4*)((u32*)outhi + (((size_t)node << 5) + (p << 2)))) = H;
}

// ---------- dense via MFMA, split-bf16 A0 only, Chebyshev fold in the weights ----------
// out = A0@(W0 - W2) + A1@W1 + Ty@(2*W2);  A1/Ty bf16-only, A0 keeps a lo plane.
// MFMAs per tile: 6 (ah*wh) + 6 (ah*wl) + 2 (a0l*wh) = 14.
#define DGRID 1250
#define DNT 5              // 1250 * 5 * 16 = 100000 rows exactly
#define LSTR 200           // u16 per LDS row for Ah (192 data + 8 pad)
#define LSTR2 72           // u16 per LDS row for Al (64 data + 8 pad)

__device__ __forceinline__ float foldW(const float* __restrict__ W, int kk, int col,
                                       int ncols) {
    float wv = W[kk * ncols + col];
    if (kk < 64) wv -= W[(kk + 128) * ncols + col];   // W0 - W2
    else if (kk >= 128) wv += wv;                     // 2 * W2
    return wv;
}

__global__ __launch_bounds__(256) void dense1_mf(const float* __restrict__ x,
                                                 const u16* __restrict__ a1h,
                                                 const u16* __restrict__ tyh,
                                                 const float* __restrict__ W,
                                                 const float* __restrict__ bias,
                                                 u16* __restrict__ ohi,
                                                 u16* __restrict__ olo) {
    __shared__ u16 Ah[16 * LSTR], Al[16 * LSTR2];
    const int tid = threadIdx.x, wid = tid >> 6, lane = tid & 63;
    const int lrow = lane & 15, lk8 = (lane >> 4) * 8;
    const int col = wid * 16 + lrow;

    bf16x8 wh[6], wl[6];
#pragma unroll
    for (int c = 0; c < 6; ++c) {
        bf16x8 h, l;
#pragma unroll
        for (int i = 0; i < 8; ++i) {
            float wv = foldW(W, c * 32 + lk8 + i, col, 64);
            u16 hb_ = f2bf(wv);
            h[i] = (short)hb_;
            l[i] = (short)f2bf(wv - bf2f(hb_));
        }
        wh[c] = h; wl[c] = l;
    }
    float bv = bias[col];
    const int srow = tid >> 4, sc4 = (tid & 15) * 4;

    for (int t = 0; t < DNT; ++t) {
        int r0 = (blockIdx.x * DNT + t) * 16;
        size_t rb = ((size_t)(r0 + srow) << 6) + sc4;
        {
            float4 v = *(const float4*)&x[rb];
            const float* vp = (const float*)&v;
            ushort4 hv, lv;
#pragma unroll
            for (int i = 0; i < 4; ++i) {
                u16 hb_ = f2bf(vp[i]);
                ((u16*)&hv)[i] = hb_;
                ((u16*)&lv)[i] = f2bf(vp[i] - bf2f(hb_));
            }
            *(ushort4*)&Ah[srow * LSTR + sc4] = hv;
            *(ushort4*)&Al[srow * LSTR2 + sc4] = lv;
        }
        *(ushort4*)&Ah[srow * LSTR + 64 + sc4] = *(const ushort4*)&a1h[rb];
        *(ushort4*)&Ah[srow * LSTR + 128 + sc4] = *(const ushort4*)&tyh[rb];
        __syncthreads();

        f32x4 acc = {bv, bv, bv, bv};
#pragma unroll
        for (int c = 0; c < 6; ++c) {
            bf16x8 ah = *(const bf16x8*)&Ah[lrow * LSTR + c * 32 + lk8];
            acc = __builtin_amdgcn_mfma_f32_16x16x32_bf16(ah, wh[c], acc, 0, 0, 0);
            acc = __builtin_amdgcn_mfma_f32_16x16x32_bf16(ah, wl[c], acc, 0, 0, 0);
        }
#pragma unroll
        for (int c = 0; c < 2; ++c) {   // A0 lo plane covers k in [0,64)
            bf16x8 al = *(const bf16x8*)&Al[lrow * LSTR2 + c * 32 + lk8];
            acc = __builtin_amdgcn_mfma_f32_16x16x32_bf16(al, wh[c], acc, 0, 0, 0);
        }
        __syncthreads();

#pragma unroll
        for (int j = 0; j < 4; ++j) {
            int row = r0 + (lane >> 4) * 4 + j;
            float v = fmaxf(acc[j], 0.0f);
            u16 hb_ = f2bf(v);
            ohi[((size_t)row << 6) + col] = hb_;
            olo[((size_t)row << 6) + col] = f2bf(v - bf2f(hb_));
        }
    }
}

__global__ __launch_bounds__(256) void dense2_mf(const u16* __restrict__ a0h,
                                                 const u16* __restrict__ a0l,
                                                 const u16* __restrict__ a1h,
                                                 const u16* __restrict__ tyh,
                                                 const float* __restrict__ W,
                                                 const float* __restrict__ bias,
                                                 float* __restrict__ out) {
    __shared__ u16 Ah[16 * LSTR], Al[16 * LSTR2];
    __shared__ float Ls[16][48];
    const int tid = threadIdx.x, wid = tid >> 6, lane = tid & 63;
    const int lrow = lane & 15, lk8 = (lane >> 4) * 8;
    const int col = wid * 16 + lrow;
    const bool act = (wid < 3);
    const bool cok = act && (col < NCLS);

    bf16x8 wh[6], wl[6];
#pragma unroll
    for (int c = 0; c < 6; ++c) {
        bf16x8 h = 0, l = 0;
        if (cok) {
#pragma unroll
            for (int i = 0; i < 8; ++i) {
                float wv = foldW(W, c * 32 + lk8 + i, col, NCLS);
                u16 hb_ = f2bf(wv);
                h[i] = (short)hb_;
                l[i] = (short)f2bf(wv - bf2f(hb_));
            }
        }
        wh[c] = h; wl[c] = l;
    }
    float bv = cok ? bias[col] : 0.0f;
    const int srow = tid >> 4, sc4 = (tid & 15) * 4;

    for (int t = 0; t < DNT; ++t) {
        int r0 = (blockIdx.x * DNT + t) * 16;
        size_t rb = ((size_t)(r0 + srow) << 6) + sc4;
        *(ushort4*)&Ah[srow * LSTR + sc4] = *(const ushort4*)&a0h[rb];
        *(ushort4*)&Al[srow * LSTR2 + sc4] = *(const ushort4*)&a0l[rb];
        *(ushort4*)&Ah[srow * LSTR + 64 + sc4] = *(const ushort4*)&a1h[rb];
        *(ushort4*)&Ah[srow * LSTR + 128 + sc4] = *(const ushort4*)&tyh[rb];
        __syncthreads();

        if (act) {
            f32x4 acc = {bv, bv, bv, bv};
#pragma unroll
            for (int c = 0; c < 6; ++c) {
                bf16x8 ah = *(const bf16x8*)&Ah[lrow * LSTR + c * 32 + lk8];
                acc = __builtin_amdgcn_mfma_f32_16x16x32_bf16(ah, wh[c], acc, 0, 0, 0);
                acc = __builtin_amdgcn_mfma_f32_16x16x32_bf16(ah, wl[c], acc, 0, 0, 0);
            }
#pragma unroll
            for (int c = 0; c < 2; ++c) {
                bf16x8 al = *(const bf16x8*)&Al[lrow * LSTR2 + c * 32 + lk8];
                acc = __builtin_amdgcn_mfma_f32_16x16x32_bf16(al, wh[c], acc, 0, 0, 0);
            }
#pragma unroll
            for (int j = 0; j < 4; ++j) Ls[(lane >> 4) * 4 + j][col] = acc[j];
        }
        __syncthreads();

        {   // softmax: 16 rows, one 16-lane group per row (4 rows per wave)
            int row = wid * 4 + (lane >> 4);
            int cg = lane & 15;
            float v0 = Ls[row][cg];
            float v1 = Ls[row][cg + 16];
            float v2 = (cg < 8) ? Ls[row][cg + 32] : -1e30f;
            float m = fmaxf(fmaxf(v0, v1), v2);
#pragma unroll
            for (int o = 8; o; o >>= 1) m = fmaxf(m, __shfl_xor(m, o));
            float e0 = expf(v0 - m), e1 = expf(v1 - m);
            float e2 = (cg < 8) ? expf(v2 - m) : 0.0f;
            float s = e0 + e1 + e2;
#pragma unroll
            for (int o = 8; o; o >>= 1) s += __shfl_xor(s, o);
            float inv = 1.0f / s;
            size_t ob = (size_t)(r0 + row) * NCLS;
            out[ob + cg] = e0 * inv;
            out[ob + cg + 16] = e1 * inv;
            if (cg < 8) out[ob + cg + 32] = e2 * inv;
        }
    }
}

// ---------------- host ----------------

extern "C" void kernel_launch(void* const* d_in, const int* in_sizes, int n_in,
                              void* d_out, int out_size, void* d_ws, size_t ws_size,
                              hipStream_t stream) {
    const float* x = (const float*)d_in[0];
    const int* edge_index = (const int*)d_in[1];
    const float* W1 = (const float*)d_in[2];
    const float* b1 = (const float*)d_in[3];
    const float* W2 = (const float*)d_in[4];
    const float* b2 = (const float*)d_in[5];
    float* out = (float*)d_out;

    const int* src = edge_index;
    const int* dst = edge_index + N_EDGES;

    char* ws = (char*)d_ws;
    size_t off = 0;
    auto carve = [&](size_t bytes) -> void* {
        void* p = ws + off;
        off = align256(off + bytes);
        return p;
    };
    int* gFillD = (int*)carve((size_t)NBUCK * 4);
    int* gFillS = (int*)carve((size_t)NBUCK * 4);
    size_t zero_bytes = off;
    u32* partD = (u32*)carve((size_t)NBUCK * CAPE * 4);     // 7.0 MB ((s<<9)|dlocal)
    u16* partS = (u16*)carve((size_t)NBUCK * CAPE * 2);     // 3.5 MB (bucket-local src)
    u32* csr = (u32*)carve((size_t)NBUCK * CAPC * 4 + 1024);// 8.4 MB (src|w15<<17)
    int2* meta = (int2*)carve((size_t)N_NODES * 8);         // 0.8 MB
    float* dis = (float*)carve((size_t)(N_NODES + 1) * 4);  // 0.4 MB
    const size_t FB = (size_t)(N_NODES + 1) * 64 * 2;       // 12.8 MB per bf16 plane
    u16* xb  = (u16*)carve(FB);
    u16* t1h = (u16*)carve(FB);   // Tx1 / Th1 hi (bf16-only)
    u16* tyh = (u16*)carve(FB);   // L.Tx1 / L.Th1 hi (bf16-only)
    u16* hh  = (u16*)carve(FB);   // h hi (gather input for layer 2)
    u16* hl  = (u16*)carve(FB);   // h lo (dense2 A0 lo plane)
    // total ~84 MB

    (void)hipMemsetAsync(d_ws, 0, zero_bytes, stream);   // gFillD/gFillS only (1.6 KB)

    pscatter_conv<<<PS_BLOCKS + CONV_BLOCKS, 256, 0, stream>>>(src, dst, gFillD, gFillS,
                                                               partD, partS, x, xb);
    build_dis<<<NBUCK, 256, 0, stream>>>(partS, gFillS, dis);
    build_csr<<<NBUCK, 256, 0, stream>>>(partD, gFillD, dis, csr, meta);

    // layer 1: Tx1 = L.x ; Ty = L.Tx1 ; h = relu(x@(W0-W2) + Tx1@W1 + Ty@2W2 + b1)
    spmm<<<SPMM_BLOCKS, 256, 0, stream>>>(xb, dis, meta, csr, t1h);
    spmm<<<SPMM_BLOCKS, 256, 0, stream>>>(t1h, dis, meta, csr, tyh);
    dense1_mf<<<DGRID, 256, 0, stream>>>(x, t1h, tyh, W1, b1, hh, hl);

    // layer 2 (t1h/tyh reused)
    spmm<<<SPMM_BLOCKS, 256, 0, stream>>>(hh, dis, meta, csr, t1h);
    spmm<<<SPMM_BLOCKS, 256, 0, stream>>>(t1h, dis, meta, csr, tyh);
    dense2_mf<<<DGRID, 256, 0, stream>>>(hh, hl, t1h, tyh, W2, b2, out);
}